// Round 5
// baseline (11883.974 us; speedup 1.0000x reference)
//
#include <hip/hip_runtime.h>
#include <math.h>

// ---------------------------------------------------------------------------
// VQ-VAE forward, fp32, workspace = 2 x 128 MiB of d_ws.
// R5 vs R4 (11.83 ms): LDS bank-conflict fix ONLY (isolate one variable).
//   conv3x3  s_in row stride 66 -> 67  (4-way conflict -> conflict-free)
//   conv4x4  s_in row stride 130 -> 131 (8-way -> 4-way; x-stride-8 caps fix)
//   convT    s_in row stride 66 -> 67  (4-way -> free)
// R4 evidence: SQ_LDS_BANK_CONFLICT 7.1e7 on conv3x3; bank math: stride%32==2
// + lane x-step 8 => 16 banks for 64 lanes. stride%32==3 => 32 banks (free).
// ---------------------------------------------------------------------------

#define RE_SIZE 786432

// ---------------- conv 1x1 (+bias, ACT: 0=none, 2=sigmoid) ----------------
template<int ACT, int CW>
__global__ __launch_bounds__(256) void conv1x1_kernel(
    const float* __restrict__ in, const float* __restrict__ w,
    const float* __restrict__ bias, float* __restrict__ out,
    int N, int Cin, int Cout, int HW) {
  extern __shared__ float wl[];                   // CW * Cin
  int co0 = blockIdx.y * CW;
  for (int i = threadIdx.x; i < CW * Cin; i += blockDim.x)
    wl[i] = w[(long)co0 * Cin + i];
  __syncthreads();
  int HW4 = HW >> 2;
  long p4 = (long)blockIdx.x * blockDim.x + threadIdx.x;
  if (p4 >= (long)N * HW4) return;
  int n = (int)(p4 / HW4), hw4 = (int)(p4 % HW4);
  const float4* inp = (const float4*)(in + (long)n * Cin * HW) + hw4;
  float4* outp = (float4*)(out + (long)n * Cout * HW) + hw4;
  float4 acc[CW];
#pragma unroll
  for (int j = 0; j < CW; ++j) { float bb = bias[co0 + j]; acc[j] = make_float4(bb, bb, bb, bb); }
  for (int ci = 0; ci < Cin; ++ci) {
    float4 v = inp[(long)ci * HW4];
#pragma unroll
    for (int j = 0; j < CW; ++j) {
      float ww = wl[j * Cin + ci];
      acc[j].x = fmaf(ww, v.x, acc[j].x);
      acc[j].y = fmaf(ww, v.y, acc[j].y);
      acc[j].z = fmaf(ww, v.z, acc[j].z);
      acc[j].w = fmaf(ww, v.w, acc[j].w);
    }
  }
#pragma unroll
  for (int j = 0; j < CW; ++j) {
    float4 v = acc[j];
    if (ACT == 2) {
      v.x = 1.f / (1.f + expf(-v.x));
      v.y = 1.f / (1.f + expf(-v.y));
      v.z = 1.f / (1.f + expf(-v.z));
      v.w = 1.f / (1.f + expf(-v.w));
    }
    outp[(long)(co0 + j) * HW4] = v;
  }
}

// ---------------- conv 3x3 s1 p1, 128->128, +bias ---------------------------
// IMODE: 0 = raw input; 1 = bn+relu fused on staged input; 2 = input is
// enc_in(x) computed on the fly (1x1 conv 3->128).
// Tile: 64x32 spatial, 8 out-ch per block, 8 px/thread. CI_T=4.
// LDS row stride 67 (odd) => conflict-free for (ty, txg*8) wave layout.
template<int IMODE>
__global__ __launch_bounds__(256) void conv3x3_kernel(
    const float* __restrict__ in, const float* __restrict__ w,
    const float* __restrict__ bias, float* __restrict__ out,
    int H, int W, const float2* __restrict__ mr,
    const float* __restrict__ xin, const float* __restrict__ w1,
    const float* __restrict__ b1) {
  constexpr int C = 128, CI_T = 4, CO_T = 8;
  __shared__ float s_in[CI_T][34][67];
  __shared__ float s_w[CO_T][CI_T][12];           // 9 taps padded to 12
  int tid = threadIdx.x;
  int tilesX = W >> 6;
  int tx0 = (blockIdx.x % tilesX) << 6;
  int ty0 = (blockIdx.x / tilesX) << 5;
  int co0 = blockIdx.y * CO_T;
  int n = blockIdx.z;
  int ty = tid >> 3, txg = (tid & 7) << 3;        // row 0..31, col 0,8,..56
  float acc[CO_T][8];
#pragma unroll
  for (int a = 0; a < CO_T; ++a)
#pragma unroll
    for (int s = 0; s < 8; ++s) acc[a][s] = 0.f;
  const long HWl = (long)H * W;
  const long ibase = (long)n * C * HWl;
  for (int ci0 = 0; ci0 < C; ci0 += CI_T) {
    for (int l = tid; l < CI_T * 34 * 66; l += 256) {
      int ci = l / (34 * 66), rem = l % (34 * 66);
      int yy = rem / 66, xx = rem % 66;
      int gy = ty0 + yy - 1, gx = tx0 + xx - 1;
      float v = 0.f;
      if ((unsigned)gy < (unsigned)H && (unsigned)gx < (unsigned)W) {
        if (IMODE == 2) {
          int c = ci0 + ci;
          const float* xp = xin + (long)n * 3 * HWl + (long)gy * W + gx;
          v = b1[c];
          v = fmaf(w1[c * 3 + 0], xp[0], v);
          v = fmaf(w1[c * 3 + 1], xp[HWl], v);
          v = fmaf(w1[c * 3 + 2], xp[2 * HWl], v);
        } else {
          v = in[ibase + (long)(ci0 + ci) * HWl + (long)gy * W + gx];
          if (IMODE == 1) {
            float2 s = mr[ci0 + ci];
            v = fmaxf((v - s.x) * s.y, 0.f);
          }
        }
      }
      s_in[ci][yy][xx] = v;
    }
    for (int l = tid; l < CO_T * CI_T * 9; l += 256) {
      int co = l / (CI_T * 9), rem = l % (CI_T * 9);
      int ci = rem / 9, k = rem % 9;
      s_w[co][ci][k] = w[((long)(co0 + co) * C + ci0 + ci) * 9 + k];
    }
    __syncthreads();
#pragma unroll
    for (int ci = 0; ci < CI_T; ++ci) {
      float r[3][10];
#pragma unroll
      for (int dy = 0; dy < 3; ++dy)
#pragma unroll
        for (int dx = 0; dx < 10; ++dx)
          r[dy][dx] = s_in[ci][ty + dy][txg + dx];
#pragma unroll
      for (int co = 0; co < CO_T; ++co) {
        const float* wp = s_w[co][ci];
        float4 w0 = *(const float4*)wp;
        float4 w4 = *(const float4*)(wp + 4);
        float w8 = wp[8];
#pragma unroll
        for (int sp = 0; sp < 8; ++sp) {
          float a = acc[co][sp];
          a = fmaf(w0.x, r[0][sp], a);
          a = fmaf(w0.y, r[0][sp + 1], a);
          a = fmaf(w0.z, r[0][sp + 2], a);
          a = fmaf(w0.w, r[1][sp], a);
          a = fmaf(w4.x, r[1][sp + 1], a);
          a = fmaf(w4.y, r[1][sp + 2], a);
          a = fmaf(w4.z, r[2][sp], a);
          a = fmaf(w4.w, r[2][sp + 1], a);
          a = fmaf(w8,   r[2][sp + 2], a);
          acc[co][sp] = a;
        }
      }
    }
    __syncthreads();
  }
  int oy = ty0 + ty, ox = tx0 + txg;
#pragma unroll
  for (int co = 0; co < CO_T; ++co) {
    float bb = bias[co0 + co];
    long rowoff = ibase + ((long)(co0 + co) * H + oy) * W + ox;
    float4 v0 = make_float4(acc[co][0] + bb, acc[co][1] + bb, acc[co][2] + bb, acc[co][3] + bb);
    float4 v1 = make_float4(acc[co][4] + bb, acc[co][5] + bb, acc[co][6] + bb, acc[co][7] + bb);
    *(float4*)(out + rowoff) = v0;
    *(float4*)(out + rowoff + 4) = v1;
  }
}

// ---------------- conv 4x4 s2 p1, 128->128, +bias +relu ---------------------
// LDS row stride 131 (8-way -> 4-way; lane x-stride 8 caps further fix).
__global__ __launch_bounds__(256) void conv4x4s2_kernel(
    const float* __restrict__ in, const float* __restrict__ w,
    const float* __restrict__ bias, float* __restrict__ out,
    int Hin, int Win) {
  constexpr int C = 128, CI_T = 2, CO_T = 16;
  int Hout = Hin >> 1, Wout = Win >> 1;
  __shared__ float s_in[CI_T][34][131];
  __shared__ float s_w[CO_T][CI_T][16];
  int tid = threadIdx.x;
  int tilesX = Wout >> 6;
  int oy0 = (blockIdx.x / tilesX) << 4;
  int ox0 = (blockIdx.x % tilesX) << 6;
  int co0 = blockIdx.y * CO_T;
  int n = blockIdx.z;
  int ty = tid >> 4, txg = tid & 15;
  float acc[CO_T][4];
#pragma unroll
  for (int a = 0; a < CO_T; ++a) acc[a][0] = acc[a][1] = acc[a][2] = acc[a][3] = 0.f;
  const long ibase = (long)n * C * Hin * Win;
  int iy0 = 2 * oy0 - 1, ix0 = 2 * ox0 - 1;
  for (int ci0 = 0; ci0 < C; ci0 += CI_T) {
    for (int l = tid; l < CI_T * 34 * 130; l += 256) {
      int ci = l / (34 * 130), rem = l % (34 * 130);
      int yy = rem / 130, xx = rem % 130;
      int gy = iy0 + yy, gx = ix0 + xx;
      float v = 0.f;
      if ((unsigned)gy < (unsigned)Hin && (unsigned)gx < (unsigned)Win)
        v = in[ibase + ((long)(ci0 + ci) * Hin + gy) * Win + gx];
      s_in[ci][yy][xx] = v;
    }
    for (int l = tid; l < CO_T * CI_T * 16; l += 256) {
      int co = l >> 5, rem = l & 31, ci = rem >> 4, k = rem & 15;
      s_w[co][ci][k] = w[((long)(co0 + co) * C + ci0 + ci) * 16 + k];
    }
    __syncthreads();
#pragma unroll
    for (int ci = 0; ci < CI_T; ++ci) {
      float r[4][10];
      int yb = ty << 1, xb = txg << 3;
#pragma unroll
      for (int dy = 0; dy < 4; ++dy)
#pragma unroll
        for (int dx = 0; dx < 10; ++dx)
          r[dy][dx] = s_in[ci][yb + dy][xb + dx];
#pragma unroll
      for (int co = 0; co < CO_T; ++co) {
        const float* wp = s_w[co][ci];
        float4 w0 = *(const float4*)wp;
        float4 w1 = *(const float4*)(wp + 4);
        float4 w2 = *(const float4*)(wp + 8);
        float4 w3 = *(const float4*)(wp + 12);
#pragma unroll
        for (int sp = 0; sp < 4; ++sp) {
          int xo = sp << 1;
          float a = acc[co][sp];
          a = fmaf(w0.x, r[0][xo], a);     a = fmaf(w0.y, r[0][xo + 1], a);
          a = fmaf(w0.z, r[0][xo + 2], a); a = fmaf(w0.w, r[0][xo + 3], a);
          a = fmaf(w1.x, r[1][xo], a);     a = fmaf(w1.y, r[1][xo + 1], a);
          a = fmaf(w1.z, r[1][xo + 2], a); a = fmaf(w1.w, r[1][xo + 3], a);
          a = fmaf(w2.x, r[2][xo], a);     a = fmaf(w2.y, r[2][xo + 1], a);
          a = fmaf(w2.z, r[2][xo + 2], a); a = fmaf(w2.w, r[2][xo + 3], a);
          a = fmaf(w3.x, r[3][xo], a);     a = fmaf(w3.y, r[3][xo + 1], a);
          a = fmaf(w3.z, r[3][xo + 2], a); a = fmaf(w3.w, r[3][xo + 3], a);
          acc[co][sp] = a;
        }
      }
    }
    __syncthreads();
  }
  const long obase = (long)n * C * Hout * Wout;
  int oy = oy0 + ty, oxb = ox0 + (txg << 2);
#pragma unroll
  for (int co = 0; co < CO_T; ++co) {
    float bb = bias[co0 + co];
    float4 v = make_float4(fmaxf(acc[co][0] + bb, 0.f), fmaxf(acc[co][1] + bb, 0.f),
                           fmaxf(acc[co][2] + bb, 0.f), fmaxf(acc[co][3] + bb, 0.f));
    *(float4*)(out + obase + ((long)(co0 + co) * Hout + oy) * Wout + oxb) = v;
  }
}

// ---------------- ConvTranspose2d(k=4,s=2,p=1), torch w (I,O,4,4), +relu ----
// LDS row stride 67 => conflict-free.
__global__ __launch_bounds__(256) void convT4x4_kernel(
    const float* __restrict__ in, const float* __restrict__ w,
    const float* __restrict__ bias, float* __restrict__ out,
    int Hin, int Win) {
  constexpr int C = 128, CI_T = 4, CO_T = 16;
  int Hout = Hin << 1, Wout = Win << 1;
  __shared__ float s_in[CI_T][18][67];
  __shared__ float s_w[CO_T][CI_T][4];
  int tid = threadIdx.x;
  int cls = blockIdx.z & 3, n = blockIdx.z >> 2;
  int py = cls >> 1, px = cls & 1;
  int tilesX = Win >> 6;
  int m0 = (blockIdx.x / tilesX) << 4;
  int x0 = (blockIdx.x % tilesX) << 6;
  int co0 = blockIdx.y * CO_T;
  int ty = tid >> 4, txg = tid & 15;
  int ky0 = py ? 0 : 1, ky1 = py ? 2 : 3;
  int dy0 = py ? 1 : 0, dy1 = py ? 0 : -1;
  int kx0 = px ? 0 : 1, kx1 = px ? 2 : 3;
  int dxA = px ? 1 : 0, dxB = px ? 0 : -1;
  float acc[CO_T][4];
#pragma unroll
  for (int a = 0; a < CO_T; ++a) acc[a][0] = acc[a][1] = acc[a][2] = acc[a][3] = 0.f;
  const long ibase = (long)n * C * Hin * Win;
  for (int ci0 = 0; ci0 < C; ci0 += CI_T) {
    for (int l = tid; l < CI_T * 18 * 66; l += 256) {
      int ci = l / (18 * 66), rem = l % (18 * 66);
      int yy = rem / 66, xx = rem % 66;
      int gy = m0 - 1 + yy, gx = x0 - 1 + xx;
      float v = 0.f;
      if ((unsigned)gy < (unsigned)Hin && (unsigned)gx < (unsigned)Win)
        v = in[ibase + ((long)(ci0 + ci) * Hin + gy) * Win + gx];
      s_in[ci][yy][xx] = v;
    }
    {
      int l = tid;  // CO_T*CI_T*4 == 256 exactly
      int co = l >> 4, rem = l & 15, ci = rem >> 2, j = rem & 3;
      int ky = (j & 2) ? ky1 : ky0;
      int kx = (j & 1) ? kx1 : kx0;
      s_w[co][ci][j] = w[((long)(ci0 + ci) * C + (co0 + co)) * 16 + ky * 4 + kx];
    }
    __syncthreads();
#pragma unroll
    for (int ci = 0; ci < CI_T; ++ci) {
      float r0v[6], r1v[6];
#pragma unroll
      for (int c2 = 0; c2 < 6; ++c2) {
        r0v[c2] = s_in[ci][ty + 1 + dy0][txg * 4 + c2];
        r1v[c2] = s_in[ci][ty + 1 + dy1][txg * 4 + c2];
      }
#pragma unroll
      for (int co = 0; co < CO_T; ++co) {
        float4 wv = *(const float4*)s_w[co][ci];
#pragma unroll
        for (int sp = 0; sp < 4; ++sp) {
          float a = acc[co][sp];
          a = fmaf(wv.x, r0v[sp + 1 + dxA], a);
          a = fmaf(wv.y, r0v[sp + 1 + dxB], a);
          a = fmaf(wv.z, r1v[sp + 1 + dxA], a);
          a = fmaf(wv.w, r1v[sp + 1 + dxB], a);
          acc[co][sp] = a;
        }
      }
    }
    __syncthreads();
  }
  const long obase = (long)n * C * Hout * Wout;
  int oy = ((m0 + ty) << 1) + py;
#pragma unroll
  for (int co = 0; co < CO_T; ++co) {
    float bb = bias[co0 + co];
    long rowoff = obase + ((long)(co0 + co) * Hout + oy) * Wout;
#pragma unroll
    for (int sp = 0; sp < 4; ++sp) {
      int ox = ((x0 + txg * 4 + sp) << 1) + px;
      out[rowoff + ox] = fmaxf(acc[co][sp] + bb, 0.f);
    }
  }
}

// ---------------- BN batch stats: mean + rsqrt(var+eps) ---------------------
__global__ __launch_bounds__(256) void bn_stats_kernel(
    const float* __restrict__ x, float2* __restrict__ mr, int N, int C, int HW) {
  int c = blockIdx.x;
  double s = 0.0, ss = 0.0;
  int HW4 = HW >> 2;
  for (int n = 0; n < N; ++n) {
    const float4* xp = (const float4*)(x + ((long)n * C + c) * HW);
    for (int i = threadIdx.x; i < HW4; i += 256) {
      float4 v = xp[i];
      s  += (double)v.x + (double)v.y + (double)v.z + (double)v.w;
      ss += (double)v.x * v.x + (double)v.y * v.y + (double)v.z * v.z + (double)v.w * v.w;
    }
  }
  __shared__ double sh_s[256], sh_ss[256];
  sh_s[threadIdx.x] = s; sh_ss[threadIdx.x] = ss;
  __syncthreads();
  for (int off = 128; off > 0; off >>= 1) {
    if (threadIdx.x < off) { sh_s[threadIdx.x] += sh_s[threadIdx.x + off];
                             sh_ss[threadIdx.x] += sh_ss[threadIdx.x + off]; }
    __syncthreads();
  }
  if (threadIdx.x == 0) {
    double cnt = (double)N * HW;
    double m = sh_s[0] / cnt;
    double var = sh_ss[0] / cnt - m * m;
    mr[c] = make_float2((float)m, (float)(1.0 / sqrt(var + 1e-5)));
  }
}

// ---------------- in-place: y = relu(bn(y) + residual) ----------------------
template<int RMODE>
__global__ __launch_bounds__(256) void bn_res_relu_kernel(
    float* __restrict__ y, const float2* __restrict__ mr,
    const float* __restrict__ res,
    const float* __restrict__ xin, const float* __restrict__ w1,
    const float* __restrict__ b1, int HW4) {
  int nc = blockIdx.y;
  int c = nc & 127, n = nc >> 7;
  float2 s = mr[c];
  int i = blockIdx.x * blockDim.x + threadIdx.x;
  if (i >= HW4) return;
  long off = (long)nc * HW4 + i;
  float4 v = ((const float4*)y)[off];
  v.x = (v.x - s.x) * s.y; v.y = (v.y - s.x) * s.y;
  v.z = (v.z - s.x) * s.y; v.w = (v.w - s.x) * s.y;
  float4 r4;
  if (RMODE == 0) {
    r4 = ((const float4*)res)[off];
  } else {
    const float4* xp = (const float4*)(xin) + (long)n * 3 * HW4 + i;
    float4 x0 = xp[0], x1 = xp[HW4], x2 = xp[2 * HW4];
    float wa = w1[c * 3 + 0], wb = w1[c * 3 + 1], wc = w1[c * 3 + 2], bb = b1[c];
    r4.x = fmaf(wa, x0.x, fmaf(wb, x1.x, fmaf(wc, x2.x, bb)));
    r4.y = fmaf(wa, x0.y, fmaf(wb, x1.y, fmaf(wc, x2.y, bb)));
    r4.z = fmaf(wa, x0.z, fmaf(wb, x1.z, fmaf(wc, x2.z, bb)));
    r4.w = fmaf(wa, x0.w, fmaf(wb, x1.w, fmaf(wc, x2.w, bb)));
  }
  v.x = fmaxf(v.x + r4.x, 0.f); v.y = fmaxf(v.y + r4.y, 0.f);
  v.z = fmaxf(v.z + r4.z, 0.f); v.w = fmaxf(v.w + r4.w, 0.f);
  ((float4*)y)[off] = v;
}

// ---------------- VQ: argmin_k ||z - e_k||^2, idx + histogram ---------------
__global__ __launch_bounds__(256) void vq_kernel(
    const float* __restrict__ z, const float* __restrict__ cb,
    float* __restrict__ idx_out, float* __restrict__ counts, int HWl) {
  __shared__ float s_z[64][65];
  __shared__ float s_cb[64][64];
  __shared__ float s_bd[4][64];
  __shared__ int   s_bk[4][64];
  int tid = threadIdx.x;
  int r0 = blockIdx.x * 64;
  for (int l = tid; l < 64 * 64; l += 256) {
    int c = l >> 6, rs = l & 63;
    int r = r0 + rs;
    int n = r / HWl, rem = r % HWl;
    s_z[rs][c] = z[((long)(n * 64 + c)) * HWl + rem];
  }
  int row = tid & 63, cg = tid >> 6;
  float best = 3.4e38f; int bestk = 0;
  for (int k0 = 0; k0 < 1024; k0 += 64) {
    __syncthreads();
    for (int l = tid; l < 4096; l += 256)
      s_cb[l >> 6][l & 63] = cb[(long)(k0 + (l >> 6)) * 64 + (l & 63)];
    __syncthreads();
#pragma unroll
    for (int j = 0; j < 16; ++j) {
      int kk = cg * 16 + j;
      const float* zp = s_z[row];
      const float* cp = s_cb[kk];
      float d = 0.f;
#pragma unroll
      for (int c = 0; c < 64; ++c) {
        float t = zp[c] - cp[c];
        d = fmaf(t, t, d);
      }
      int k = k0 + kk;
      if (d < best) { best = d; bestk = k; }
    }
  }
  s_bd[cg][row] = best; s_bk[cg][row] = bestk;
  __syncthreads();
  if (tid < 64) {
    float bd = s_bd[0][tid]; int bk = s_bk[0][tid];
#pragma unroll
    for (int g = 1; g < 4; ++g) {
      float d2 = s_bd[g][tid]; int k2 = s_bk[g][tid];
      if (d2 < bd || (d2 == bd && k2 < bk)) { bd = d2; bk = k2; }
    }
    idx_out[r0 + tid] = (float)bk;
    atomicAdd(&counts[bk], 1.0f);
  }
}

// ---------------- zero small buffer ----------------------------------------
__global__ __launch_bounds__(256) void zero_kernel(float* __restrict__ p, int n) {
  int i = blockIdx.x * 256 + threadIdx.x;
  if (i < n) p[i] = 0.f;
}

// ---------------- loss = sum p log p  (= -entropy) --------------------------
__global__ __launch_bounds__(256) void entropy_kernel(
    const float* __restrict__ counts, float* __restrict__ loss_out) {
  __shared__ double sh[256];
  int tid = threadIdx.x;
  double s = 0.0;
  for (int i = tid; i < 1024; i += 256) s += (double)counts[i] + 1e-6;
  sh[tid] = s; __syncthreads();
  for (int off = 128; off > 0; off >>= 1) {
    if (tid < off) sh[tid] += sh[tid + off];
    __syncthreads();
  }
  double S = sh[0];
  __syncthreads();
  double pl = 0.0;
  for (int i = tid; i < 1024; i += 256) {
    double p = ((double)counts[i] + 1e-6) / S;
    pl += p * log(p);
  }
  sh[tid] = pl; __syncthreads();
  for (int off = 128; off > 0; off >>= 1) {
    if (tid < off) sh[tid] += sh[tid + off];
    __syncthreads();
  }
  if (tid == 0) loss_out[0] = (float)sh[0];
}

// ---------------------------------------------------------------------------
extern "C" void kernel_launch(void* const* d_in, const int* in_sizes, int n_in,
                              void* d_out, int out_size, void* d_ws, size_t ws_size,
                              hipStream_t stream) {
  (void)in_sizes; (void)n_in; (void)out_size; (void)ws_size;
  const float* x          = (const float*)d_in[0];
  const float* enc_in_w   = (const float*)d_in[1];
  const float* enc_in_b   = (const float*)d_in[2];
  const float* enc_res_w1 = (const float*)d_in[3];
  const float* enc_res_b1 = (const float*)d_in[4];
  const float* enc_res_w2 = (const float*)d_in[5];
  const float* enc_res_b2 = (const float*)d_in[6];
  const float* enc_down_w = (const float*)d_in[7];
  const float* enc_down_b = (const float*)d_in[8];
  const float* enc_out_w  = (const float*)d_in[9];
  const float* enc_out_b  = (const float*)d_in[10];
  const float* dec_in_w   = (const float*)d_in[11];
  const float* dec_in_b   = (const float*)d_in[12];
  const float* dec_res_w1 = (const float*)d_in[13];
  const float* dec_res_b1 = (const float*)d_in[14];
  const float* dec_res_w2 = (const float*)d_in[15];
  const float* dec_res_b2 = (const float*)d_in[16];
  const float* dec_up_w   = (const float*)d_in[17];
  const float* dec_up_b   = (const float*)d_in[18];
  const float* dec_out_w  = (const float*)d_in[19];
  const float* dec_out_b  = (const float*)d_in[20];
  const float* codebook   = (const float*)d_in[21];
  float* out = (float*)d_out;

  // Workspace: EXACTLY two 128-MiB fp32 buffers.
  const long BIG = 33554432;
  const long S1 = 8388608, S2 = 16777216, S3 = 25165824;
  float* P0 = (float*)d_ws;
  float* P1 = P0 + BIG;
  // Small scratch in d_out[0:1280) — recon overwrites it at the end.
  float2* mr  = (float2*)out;
  float* hist = out + 256;

  const int W3 = 128 * 128 * 9, W4 = 128 * 128 * 16, BS = 128;

  // conv3x3 grids: (W/64)*(H/32) tiles, 16 co-blocks, 4 batch
  const dim3 g256(32, 16, 4), g128(8, 16, 4), g64(2, 16, 4);

  // ===================== encoder =====================
  conv3x3_kernel<2><<<g256, 256, 0, stream>>>(
      nullptr, enc_res_w1, enc_res_b1, P0, 256, 256, nullptr, x, enc_in_w, enc_in_b);
  bn_stats_kernel<<<128, 256, 0, stream>>>(P0, mr, 4, 128, 65536);
  conv3x3_kernel<1><<<g256, 256, 0, stream>>>(
      P0, enc_res_w2, enc_res_b2, P1, 256, 256, mr, nullptr, nullptr, nullptr);
  bn_stats_kernel<<<128, 256, 0, stream>>>(P1, mr, 4, 128, 65536);
  bn_res_relu_kernel<1><<<dim3(64, 512), 256, 0, stream>>>(
      P1, mr, nullptr, x, enc_in_w, enc_in_b, 16384);
  conv4x4s2_kernel<<<dim3(16, 8, 4), 256, 0, stream>>>(P1, enc_down_w, enc_down_b, P0, 256, 256);

  conv3x3_kernel<0><<<g128, 256, 0, stream>>>(
      P0, enc_res_w1 + W3, enc_res_b1 + BS, P0 + S1, 128, 128, nullptr, nullptr, nullptr, nullptr);
  bn_stats_kernel<<<128, 256, 0, stream>>>(P0 + S1, mr, 4, 128, 16384);
  conv3x3_kernel<1><<<g128, 256, 0, stream>>>(
      P0 + S1, enc_res_w2 + W3, enc_res_b2 + BS, P0 + S2, 128, 128, mr, nullptr, nullptr, nullptr);
  bn_stats_kernel<<<128, 256, 0, stream>>>(P0 + S2, mr, 4, 128, 16384);
  bn_res_relu_kernel<0><<<dim3(16, 512), 256, 0, stream>>>(
      P0 + S2, mr, P0, nullptr, nullptr, nullptr, 4096);
  conv4x4s2_kernel<<<dim3(4, 8, 4), 256, 0, stream>>>(
      P0 + S2, enc_down_w + W4, enc_down_b + BS, P0 + S3, 128, 128);

  conv1x1_kernel<0, 16><<<dim3(16, 4), 256, 16 * 128 * 4, stream>>>(
      P0 + S3, enc_out_w, enc_out_b, P1, 4, 128, 64, 4096);

  // ===================== VQ =====================
  zero_kernel<<<4, 256, 0, stream>>>(hist, 1024);
  vq_kernel<<<256, 256, 0, stream>>>(P1, codebook, out + RE_SIZE + 1, hist, 4096);
  entropy_kernel<<<1, 256, 0, stream>>>(hist, out + RE_SIZE);

  // ===================== decoder =====================
  conv1x1_kernel<0, 16><<<dim3(16, 8), 256, 16 * 64 * 4, stream>>>(
      P1, dec_in_w, dec_in_b, P0, 4, 64, 128, 4096);

  conv3x3_kernel<0><<<g64, 256, 0, stream>>>(
      P0, dec_res_w1, dec_res_b1, P0 + S1, 64, 64, nullptr, nullptr, nullptr, nullptr);
  bn_stats_kernel<<<128, 256, 0, stream>>>(P0 + S1, mr, 4, 128, 4096);
  conv3x3_kernel<1><<<g64, 256, 0, stream>>>(
      P0 + S1, dec_res_w2, dec_res_b2, P0 + S2, 64, 64, mr, nullptr, nullptr, nullptr);
  bn_stats_kernel<<<128, 256, 0, stream>>>(P0 + S2, mr, 4, 128, 4096);
  bn_res_relu_kernel<0><<<dim3(4, 512), 256, 0, stream>>>(
      P0 + S2, mr, P0, nullptr, nullptr, nullptr, 1024);
  convT4x4_kernel<<<dim3(4, 8, 16), 256, 0, stream>>>(P0 + S2, dec_up_w, dec_up_b, P0 + S3, 64, 64);

  conv3x3_kernel<0><<<g128, 256, 0, stream>>>(
      P0 + S3, dec_res_w1 + W3, dec_res_b1 + BS, P1, 128, 128, nullptr, nullptr, nullptr, nullptr);
  bn_stats_kernel<<<128, 256, 0, stream>>>(P1, mr, 4, 128, 16384);
  conv3x3_kernel<1><<<g128, 256, 0, stream>>>(
      P1, dec_res_w2 + W3, dec_res_b2 + BS, P1 + S1, 128, 128, mr, nullptr, nullptr, nullptr);
  bn_stats_kernel<<<128, 256, 0, stream>>>(P1 + S1, mr, 4, 128, 16384);
  bn_res_relu_kernel<0><<<dim3(16, 512), 256, 0, stream>>>(
      P1 + S1, mr, P0 + S3, nullptr, nullptr, nullptr, 4096);
  convT4x4_kernel<<<dim3(16, 8, 16), 256, 0, stream>>>(
      P1 + S1, dec_up_w + W4, dec_up_b + BS, P0, 128, 128);

  conv1x1_kernel<2, 3><<<dim3(256, 1), 256, 3 * 128 * 4, stream>>>(
      P0, dec_out_w, dec_out_b, out, 4, 128, 3, 65536);
}

// Round 6
// 5363.872 us; speedup vs baseline: 2.2156x; 2.2156x over previous
//
#include <hip/hip_runtime.h>
#include <math.h>

// ---------------------------------------------------------------------------
// VQ-VAE forward. R6: conv3x3 rewritten as split-bf16 (bf16x2, 3-term) MFMA.
//   D = Ah*Bh + Ah*Bl + Al*Bh  (rel err ~2^-17, fp32-like)
//   mfma_f32_16x16x32_bf16; A=W[16co][32k], B=X[32k][16px]
//   A-frag: m=lane&15, k=(lane>>4)*8+j ; B-frag: n=lane&15, k=(lane>>4)*8+j
//   C/D:    col=lane&15 (px), row=(lane>>4)*4+reg (co)      [guide §3, m89/m91]
// Block: 4 waves x 32co = 128co, px tile 8x16=128. K-loop: 4 ci-chunks x 9 taps.
// X staged hi/lo in LDS [cig(4)][px(180)][8ci] -> B-frag = one ds_read_b128.
// W pre-split per layer (wsplit_kernel) into frag-ordered hi/lo in d_out
// scratch -> A-frag = one coalesced global 16B load (L2-resident, no barriers).
// Everything else (conv4x4s2/convT/conv1x1/bn/vq) unchanged from R5.
// ---------------------------------------------------------------------------

#define RE_SIZE 786432

typedef float f32x4 __attribute__((ext_vector_type(4)));
typedef short bf16x8 __attribute__((ext_vector_type(8)));

__device__ __forceinline__ unsigned short f2bf(float f) {
  unsigned u = __float_as_uint(f);
  return (unsigned short)((u + 0x7fffu + ((u >> 16) & 1u)) >> 16);   // RNE
}
__device__ __forceinline__ float bf2f(unsigned short h) {
  return __uint_as_float(((unsigned)h) << 16);
}

// ---------------- weight pre-split into MFMA A-frag order -------------------
// layout: [cc(4)][tap(9)][mt(8)][lane(64)][j(8)]  (147456 elems)
// co = mt*16 + (lane&15); ci = cc*32 + (lane>>4)*8 + j; src = w[co][ci][tap]
__global__ __launch_bounds__(256) void wsplit_kernel(
    const float* __restrict__ w, unsigned short* __restrict__ wh,
    unsigned short* __restrict__ wl) {
  int id = blockIdx.x * 256 + threadIdx.x;        // grid = 576 blocks
  int j = id & 7, lane = (id >> 3) & 63, rest = id >> 9;
  int mt = rest & 7, rest2 = rest >> 3;
  int tap = rest2 % 9, cc = rest2 / 9;
  int co = mt * 16 + (lane & 15);
  int ci = cc * 32 + (lane >> 4) * 8 + j;
  float v = w[((long)co * 128 + ci) * 9 + tap];
  unsigned short h = f2bf(v);
  wh[id] = h;
  wl[id] = f2bf(v - bf2f(h));
}

// ---------------- conv 3x3 s1 p1, 128->128, +bias — split-bf16 MFMA ---------
// IMODE: 0 raw; 1 bn+relu fused on staged input; 2 input = enc_in(x) on-the-fly.
template<int IMODE>
__global__ __launch_bounds__(256) void conv3x3_mfma_kernel(
    const float* __restrict__ in, const unsigned short* __restrict__ wh,
    const unsigned short* __restrict__ wl, const float* __restrict__ bias,
    float* __restrict__ out, int H, int W, const float2* __restrict__ mr,
    const float* __restrict__ xin, const float* __restrict__ w1,
    const float* __restrict__ b1) {
  __shared__ __align__(16) unsigned short s_xh[5760];   // [cig4][px180][8ci]
  __shared__ __align__(16) unsigned short s_xl[5760];
  int tid = threadIdx.x, wv = tid >> 6, lane = tid & 63;
  int q = lane >> 4, c15 = lane & 15;
  int tilesX = W >> 4;
  int tx0 = (blockIdx.x % tilesX) << 4;
  int ty0 = (blockIdx.x / tilesX) << 3;
  int n = blockIdx.z;
  long HWl = (long)H * W;
  long ibase = (long)n * 128 * HWl;
  f32x4 acc[2][8];
#pragma unroll
  for (int a = 0; a < 2; ++a)
#pragma unroll
    for (int b = 0; b < 8; ++b) acc[a][b] = (f32x4){0.f, 0.f, 0.f, 0.f};

  for (int cc = 0; cc < 4; ++cc) {
    __syncthreads();
    // ---- stage X chunk (32 ci) with halo: 10 rows x 18 cols, hi/lo bf16 ----
    for (int l = tid; l < 720; l += 256) {
      int cig = l / 180, px = l % 180;
      int y = px / 18, x = px % 18;
      int gy = ty0 + y - 1, gx = tx0 + x - 1;
      float v[8];
      if ((unsigned)gy < (unsigned)H && (unsigned)gx < (unsigned)W) {
        if (IMODE == 2) {
          const float* xp = xin + (long)n * 3 * HWl + (long)gy * W + gx;
          float x0 = xp[0], x1 = xp[HWl], x2 = xp[2 * HWl];
#pragma unroll
          for (int c = 0; c < 8; ++c) {
            int ci = cc * 32 + cig * 8 + c;
            v[c] = fmaf(w1[ci * 3 + 0], x0,
                   fmaf(w1[ci * 3 + 1], x1,
                   fmaf(w1[ci * 3 + 2], x2, b1[ci])));
          }
        } else {
          const float* ip = in + ibase + (long)(cc * 32 + cig * 8) * HWl
                            + (long)gy * W + gx;
#pragma unroll
          for (int c = 0; c < 8; ++c) v[c] = ip[(long)c * HWl];
          if (IMODE == 1) {
#pragma unroll
            for (int c = 0; c < 8; ++c) {
              float2 s = mr[cc * 32 + cig * 8 + c];
              v[c] = fmaxf((v[c] - s.x) * s.y, 0.f);
            }
          }
        }
      } else {
#pragma unroll
        for (int c = 0; c < 8; ++c) v[c] = 0.f;
      }
      bf16x8 hv, lv;
#pragma unroll
      for (int c = 0; c < 8; ++c) {
        unsigned short h = f2bf(v[c]);
        hv[c] = (short)h;
        lv[c] = (short)f2bf(v[c] - bf2f(h));
      }
      *(bf16x8*)(s_xh + l * 8) = hv;
      *(bf16x8*)(s_xl + l * 8) = lv;
    }
    __syncthreads();

    // ---- 9 taps: A from global (frag-ordered), B from LDS ----
    for (int tap = 0; tap < 9; ++tap) {
      int dy = tap / 3, dx = tap % 3;                 // 0..2 == -1..+1 via halo
      long fbase = (long)((cc * 9 + tap) * 8) * 64;   // bf16x8 units
      const bf16x8* aph = (const bf16x8*)wh + fbase;
      const bf16x8* apl = (const bf16x8*)wl + fbase;
      bf16x8 ah0 = aph[(2 * wv) * 64 + lane];
      bf16x8 ah1 = aph[(2 * wv + 1) * 64 + lane];
      bf16x8 al0 = apl[(2 * wv) * 64 + lane];
      bf16x8 al1 = apl[(2 * wv + 1) * 64 + lane];
      int xoff = (q * 180 + dy * 18 + c15 + dx) * 8;  // + nn*18*8 per row
#pragma unroll
      for (int nn = 0; nn < 8; ++nn) {
        bf16x8 bh = *(const bf16x8*)(s_xh + xoff + nn * 144);
        bf16x8 bl = *(const bf16x8*)(s_xl + xoff + nn * 144);
        acc[0][nn] = __builtin_amdgcn_mfma_f32_16x16x32_bf16(ah0, bh, acc[0][nn], 0, 0, 0);
        acc[0][nn] = __builtin_amdgcn_mfma_f32_16x16x32_bf16(ah0, bl, acc[0][nn], 0, 0, 0);
        acc[0][nn] = __builtin_amdgcn_mfma_f32_16x16x32_bf16(al0, bh, acc[0][nn], 0, 0, 0);
        acc[1][nn] = __builtin_amdgcn_mfma_f32_16x16x32_bf16(ah1, bh, acc[1][nn], 0, 0, 0);
        acc[1][nn] = __builtin_amdgcn_mfma_f32_16x16x32_bf16(ah1, bl, acc[1][nn], 0, 0, 0);
        acc[1][nn] = __builtin_amdgcn_mfma_f32_16x16x32_bf16(al1, bh, acc[1][nn], 0, 0, 0);
      }
    }
  }
  // ---- epilogue: D row = co_local = q*4+r, col = px_local = c15 ----
  float bb[2][4];
#pragma unroll
  for (int mt2 = 0; mt2 < 2; ++mt2)
#pragma unroll
    for (int r = 0; r < 4; ++r)
      bb[mt2][r] = bias[(wv * 2 + mt2) * 16 + q * 4 + r];
#pragma unroll
  for (int mt2 = 0; mt2 < 2; ++mt2) {
    int co0 = (wv * 2 + mt2) * 16 + q * 4;
#pragma unroll
    for (int nn = 0; nn < 8; ++nn) {
      long pxoff = ibase + (long)(ty0 + nn) * W + tx0 + c15;
#pragma unroll
      for (int r = 0; r < 4; ++r)
        out[pxoff + (long)(co0 + r) * HWl] = acc[mt2][nn][r] + bb[mt2][r];
    }
  }
}

// ---------------- conv 1x1 (+bias, ACT: 0=none, 2=sigmoid) ----------------
template<int ACT, int CW>
__global__ __launch_bounds__(256) void conv1x1_kernel(
    const float* __restrict__ in, const float* __restrict__ w,
    const float* __restrict__ bias, float* __restrict__ out,
    int N, int Cin, int Cout, int HW) {
  extern __shared__ float wl[];
  int co0 = blockIdx.y * CW;
  for (int i = threadIdx.x; i < CW * Cin; i += blockDim.x)
    wl[i] = w[(long)co0 * Cin + i];
  __syncthreads();
  int HW4 = HW >> 2;
  long p4 = (long)blockIdx.x * blockDim.x + threadIdx.x;
  if (p4 >= (long)N * HW4) return;
  int n = (int)(p4 / HW4), hw4 = (int)(p4 % HW4);
  const float4* inp = (const float4*)(in + (long)n * Cin * HW) + hw4;
  float4* outp = (float4*)(out + (long)n * Cout * HW) + hw4;
  float4 acc[CW];
#pragma unroll
  for (int j = 0; j < CW; ++j) { float bb = bias[co0 + j]; acc[j] = make_float4(bb, bb, bb, bb); }
  for (int ci = 0; ci < Cin; ++ci) {
    float4 v = inp[(long)ci * HW4];
#pragma unroll
    for (int j = 0; j < CW; ++j) {
      float ww = wl[j * Cin + ci];
      acc[j].x = fmaf(ww, v.x, acc[j].x);
      acc[j].y = fmaf(ww, v.y, acc[j].y);
      acc[j].z = fmaf(ww, v.z, acc[j].z);
      acc[j].w = fmaf(ww, v.w, acc[j].w);
    }
  }
#pragma unroll
  for (int j = 0; j < CW; ++j) {
    float4 v = acc[j];
    if (ACT == 2) {
      v.x = 1.f / (1.f + expf(-v.x));
      v.y = 1.f / (1.f + expf(-v.y));
      v.z = 1.f / (1.f + expf(-v.z));
      v.w = 1.f / (1.f + expf(-v.w));
    }
    outp[(long)(co0 + j) * HW4] = v;
  }
}

// ---------------- conv 4x4 s2 p1, 128->128, +bias +relu ---------------------
__global__ __launch_bounds__(256) void conv4x4s2_kernel(
    const float* __restrict__ in, const float* __restrict__ w,
    const float* __restrict__ bias, float* __restrict__ out,
    int Hin, int Win) {
  constexpr int C = 128, CI_T = 2, CO_T = 16;
  int Hout = Hin >> 1, Wout = Win >> 1;
  __shared__ float s_in[CI_T][34][131];
  __shared__ float s_w[CO_T][CI_T][16];
  int tid = threadIdx.x;
  int tilesX = Wout >> 6;
  int oy0 = (blockIdx.x / tilesX) << 4;
  int ox0 = (blockIdx.x % tilesX) << 6;
  int co0 = blockIdx.y * CO_T;
  int n = blockIdx.z;
  int ty = tid >> 4, txg = tid & 15;
  float acc[CO_T][4];
#pragma unroll
  for (int a = 0; a < CO_T; ++a) acc[a][0] = acc[a][1] = acc[a][2] = acc[a][3] = 0.f;
  const long ibase = (long)n * C * Hin * Win;
  int iy0 = 2 * oy0 - 1, ix0 = 2 * ox0 - 1;
  for (int ci0 = 0; ci0 < C; ci0 += CI_T) {
    for (int l = tid; l < CI_T * 34 * 130; l += 256) {
      int ci = l / (34 * 130), rem = l % (34 * 130);
      int yy = rem / 130, xx = rem % 130;
      int gy = iy0 + yy, gx = ix0 + xx;
      float v = 0.f;
      if ((unsigned)gy < (unsigned)Hin && (unsigned)gx < (unsigned)Win)
        v = in[ibase + ((long)(ci0 + ci) * Hin + gy) * Win + gx];
      s_in[ci][yy][xx] = v;
    }
    for (int l = tid; l < CO_T * CI_T * 16; l += 256) {
      int co = l >> 5, rem = l & 31, ci = rem >> 4, k = rem & 15;
      s_w[co][ci][k] = w[((long)(co0 + co) * C + ci0 + ci) * 16 + k];
    }
    __syncthreads();
#pragma unroll
    for (int ci = 0; ci < CI_T; ++ci) {
      float r[4][10];
      int yb = ty << 1, xb = txg << 3;
#pragma unroll
      for (int dy = 0; dy < 4; ++dy)
#pragma unroll
        for (int dx = 0; dx < 10; ++dx)
          r[dy][dx] = s_in[ci][yb + dy][xb + dx];
#pragma unroll
      for (int co = 0; co < CO_T; ++co) {
        const float* wp = s_w[co][ci];
        float4 w0 = *(const float4*)wp;
        float4 w1 = *(const float4*)(wp + 4);
        float4 w2 = *(const float4*)(wp + 8);
        float4 w3 = *(const float4*)(wp + 12);
#pragma unroll
        for (int sp = 0; sp < 4; ++sp) {
          int xo = sp << 1;
          float a = acc[co][sp];
          a = fmaf(w0.x, r[0][xo], a);     a = fmaf(w0.y, r[0][xo + 1], a);
          a = fmaf(w0.z, r[0][xo + 2], a); a = fmaf(w0.w, r[0][xo + 3], a);
          a = fmaf(w1.x, r[1][xo], a);     a = fmaf(w1.y, r[1][xo + 1], a);
          a = fmaf(w1.z, r[1][xo + 2], a); a = fmaf(w1.w, r[1][xo + 3], a);
          a = fmaf(w2.x, r[2][xo], a);     a = fmaf(w2.y, r[2][xo + 1], a);
          a = fmaf(w2.z, r[2][xo + 2], a); a = fmaf(w2.w, r[2][xo + 3], a);
          a = fmaf(w3.x, r[3][xo], a);     a = fmaf(w3.y, r[3][xo + 1], a);
          a = fmaf(w3.z, r[3][xo + 2], a); a = fmaf(w3.w, r[3][xo + 3], a);
          acc[co][sp] = a;
        }
      }
    }
    __syncthreads();
  }
  const long obase = (long)n * C * Hout * Wout;
  int oy = oy0 + ty, oxb = ox0 + (txg << 2);
#pragma unroll
  for (int co = 0; co < CO_T; ++co) {
    float bb = bias[co0 + co];
    float4 v = make_float4(fmaxf(acc[co][0] + bb, 0.f), fmaxf(acc[co][1] + bb, 0.f),
                           fmaxf(acc[co][2] + bb, 0.f), fmaxf(acc[co][3] + bb, 0.f));
    *(float4*)(out + obase + ((long)(co0 + co) * Hout + oy) * Wout + oxb) = v;
  }
}

// ---------------- ConvTranspose2d(k=4,s=2,p=1), torch w (I,O,4,4), +relu ----
__global__ __launch_bounds__(256) void convT4x4_kernel(
    const float* __restrict__ in, const float* __restrict__ w,
    const float* __restrict__ bias, float* __restrict__ out,
    int Hin, int Win) {
  constexpr int C = 128, CI_T = 4, CO_T = 16;
  int Hout = Hin << 1, Wout = Win << 1;
  __shared__ float s_in[CI_T][18][67];
  __shared__ float s_w[CO_T][CI_T][4];
  int tid = threadIdx.x;
  int cls = blockIdx.z & 3, n = blockIdx.z >> 2;
  int py = cls >> 1, px = cls & 1;
  int tilesX = Win >> 6;
  int m0 = (blockIdx.x / tilesX) << 4;
  int x0 = (blockIdx.x % tilesX) << 6;
  int co0 = blockIdx.y * CO_T;
  int ty = tid >> 4, txg = tid & 15;
  int ky0 = py ? 0 : 1, ky1 = py ? 2 : 3;
  int dy0 = py ? 1 : 0, dy1 = py ? 0 : -1;
  int kx0 = px ? 0 : 1, kx1 = px ? 2 : 3;
  int dxA = px ? 1 : 0, dxB = px ? 0 : -1;
  float acc[CO_T][4];
#pragma unroll
  for (int a = 0; a < CO_T; ++a) acc[a][0] = acc[a][1] = acc[a][2] = acc[a][3] = 0.f;
  const long ibase = (long)n * C * Hin * Win;
  for (int ci0 = 0; ci0 < C; ci0 += CI_T) {
    for (int l = tid; l < CI_T * 18 * 66; l += 256) {
      int ci = l / (18 * 66), rem = l % (18 * 66);
      int yy = rem / 66, xx = rem % 66;
      int gy = m0 - 1 + yy, gx = x0 - 1 + xx;
      float v = 0.f;
      if ((unsigned)gy < (unsigned)Hin && (unsigned)gx < (unsigned)Win)
        v = in[ibase + ((long)(ci0 + ci) * Hin + gy) * Win + gx];
      s_in[ci][yy][xx] = v;
    }
    {
      int l = tid;
      int co = l >> 4, rem = l & 15, ci = rem >> 2, j = rem & 3;
      int ky = (j & 2) ? ky1 : ky0;
      int kx = (j & 1) ? kx1 : kx0;
      s_w[co][ci][j] = w[((long)(ci0 + ci) * C + (co0 + co)) * 16 + ky * 4 + kx];
    }
    __syncthreads();
#pragma unroll
    for (int ci = 0; ci < CI_T; ++ci) {
      float r0v[6], r1v[6];
#pragma unroll
      for (int c2 = 0; c2 < 6; ++c2) {
        r0v[c2] = s_in[ci][ty + 1 + dy0][txg * 4 + c2];
        r1v[c2] = s_in[ci][ty + 1 + dy1][txg * 4 + c2];
      }
#pragma unroll
      for (int co = 0; co < CO_T; ++co) {
        float4 wv = *(const float4*)s_w[co][ci];
#pragma unroll
        for (int sp = 0; sp < 4; ++sp) {
          float a = acc[co][sp];
          a = fmaf(wv.x, r0v[sp + 1 + dxA], a);
          a = fmaf(wv.y, r0v[sp + 1 + dxB], a);
          a = fmaf(wv.z, r1v[sp + 1 + dxA], a);
          a = fmaf(wv.w, r1v[sp + 1 + dxB], a);
          acc[co][sp] = a;
        }
      }
    }
    __syncthreads();
  }
  const long obase = (long)n * C * Hout * Wout;
  int oy = ((m0 + ty) << 1) + py;
#pragma unroll
  for (int co = 0; co < CO_T; ++co) {
    float bb = bias[co0 + co];
    long rowoff = obase + ((long)(co0 + co) * Hout + oy) * Wout;
#pragma unroll
    for (int sp = 0; sp < 4; ++sp) {
      int ox = ((x0 + txg * 4 + sp) << 1) + px;
      out[rowoff + ox] = fmaxf(acc[co][sp] + bb, 0.f);
    }
  }
}

// ---------------- BN batch stats: mean + rsqrt(var+eps) ---------------------
__global__ __launch_bounds__(256) void bn_stats_kernel(
    const float* __restrict__ x, float2* __restrict__ mr, int N, int C, int HW) {
  int c = blockIdx.x;
  double s = 0.0, ss = 0.0;
  int HW4 = HW >> 2;
  for (int n = 0; n < N; ++n) {
    const float4* xp = (const float4*)(x + ((long)n * C + c) * HW);
    for (int i = threadIdx.x; i < HW4; i += 256) {
      float4 v = xp[i];
      s  += (double)v.x + (double)v.y + (double)v.z + (double)v.w;
      ss += (double)v.x * v.x + (double)v.y * v.y + (double)v.z * v.z + (double)v.w * v.w;
    }
  }
  __shared__ double sh_s[256], sh_ss[256];
  sh_s[threadIdx.x] = s; sh_ss[threadIdx.x] = ss;
  __syncthreads();
  for (int off = 128; off > 0; off >>= 1) {
    if (threadIdx.x < off) { sh_s[threadIdx.x] += sh_s[threadIdx.x + off];
                             sh_ss[threadIdx.x] += sh_ss[threadIdx.x + off]; }
    __syncthreads();
  }
  if (threadIdx.x == 0) {
    double cnt = (double)N * HW;
    double m = sh_s[0] / cnt;
    double var = sh_ss[0] / cnt - m * m;
    mr[c] = make_float2((float)m, (float)(1.0 / sqrt(var + 1e-5)));
  }
}

// ---------------- in-place: y = relu(bn(y) + residual) ----------------------
template<int RMODE>
__global__ __launch_bounds__(256) void bn_res_relu_kernel(
    float* __restrict__ y, const float2* __restrict__ mr,
    const float* __restrict__ res,
    const float* __restrict__ xin, const float* __restrict__ w1,
    const float* __restrict__ b1, int HW4) {
  int nc = blockIdx.y;
  int c = nc & 127, n = nc >> 7;
  float2 s = mr[c];
  int i = blockIdx.x * blockDim.x + threadIdx.x;
  if (i >= HW4) return;
  long off = (long)nc * HW4 + i;
  float4 v = ((const float4*)y)[off];
  v.x = (v.x - s.x) * s.y; v.y = (v.y - s.x) * s.y;
  v.z = (v.z - s.x) * s.y; v.w = (v.w - s.x) * s.y;
  float4 r4;
  if (RMODE == 0) {
    r4 = ((const float4*)res)[off];
  } else {
    const float4* xp = (const float4*)(xin) + (long)n * 3 * HW4 + i;
    float4 x0 = xp[0], x1 = xp[HW4], x2 = xp[2 * HW4];
    float wa = w1[c * 3 + 0], wb = w1[c * 3 + 1], wc = w1[c * 3 + 2], bb = b1[c];
    r4.x = fmaf(wa, x0.x, fmaf(wb, x1.x, fmaf(wc, x2.x, bb)));
    r4.y = fmaf(wa, x0.y, fmaf(wb, x1.y, fmaf(wc, x2.y, bb)));
    r4.z = fmaf(wa, x0.z, fmaf(wb, x1.z, fmaf(wc, x2.z, bb)));
    r4.w = fmaf(wa, x0.w, fmaf(wb, x1.w, fmaf(wc, x2.w, bb)));
  }
  v.x = fmaxf(v.x + r4.x, 0.f); v.y = fmaxf(v.y + r4.y, 0.f);
  v.z = fmaxf(v.z + r4.z, 0.f); v.w = fmaxf(v.w + r4.w, 0.f);
  ((float4*)y)[off] = v;
}

// ---------------- VQ: argmin_k ||z - e_k||^2, idx + histogram ---------------
__global__ __launch_bounds__(256) void vq_kernel(
    const float* __restrict__ z, const float* __restrict__ cb,
    float* __restrict__ idx_out, float* __restrict__ counts, int HWl) {
  __shared__ float s_z[64][65];
  __shared__ float s_cb[64][64];
  __shared__ float s_bd[4][64];
  __shared__ int   s_bk[4][64];
  int tid = threadIdx.x;
  int r0 = blockIdx.x * 64;
  for (int l = tid; l < 64 * 64; l += 256) {
    int c = l >> 6, rs = l & 63;
    int r = r0 + rs;
    int n = r / HWl, rem = r % HWl;
    s_z[rs][c] = z[((long)(n * 64 + c)) * HWl + rem];
  }
  int row = tid & 63, cg = tid >> 6;
  float best = 3.4e38f; int bestk = 0;
  for (int k0 = 0; k0 < 1024; k0 += 64) {
    __syncthreads();
    for (int l = tid; l < 4096; l += 256)
      s_cb[l >> 6][l & 63] = cb[(long)(k0 + (l >> 6)) * 64 + (l & 63)];
    __syncthreads();
#pragma unroll
    for (int j = 0; j < 16; ++j) {
      int kk = cg * 16 + j;
      const float* zp = s_z[row];
      const float* cp = s_cb[kk];
      float d = 0.f;
#pragma unroll
      for (int c = 0; c < 64; ++c) {
        float t = zp[c] - cp[c];
        d = fmaf(t, t, d);
      }
      int k = k0 + kk;
      if (d < best) { best = d; bestk = k; }
    }
  }
  s_bd[cg][row] = best; s_bk[cg][row] = bestk;
  __syncthreads();
  if (tid < 64) {
    float bd = s_bd[0][tid]; int bk = s_bk[0][tid];
#pragma unroll
    for (int g = 1; g < 4; ++g) {
      float d2 = s_bd[g][tid]; int k2 = s_bk[g][tid];
      if (d2 < bd || (d2 == bd && k2 < bk)) { bd = d2; bk = k2; }
    }
    idx_out[r0 + tid] = (float)bk;
    atomicAdd(&counts[bk], 1.0f);
  }
}

// ---------------- zero small buffer ----------------------------------------
__global__ __launch_bounds__(256) void zero_kernel(float* __restrict__ p, int n) {
  int i = blockIdx.x * 256 + threadIdx.x;
  if (i < n) p[i] = 0.f;
}

// ---------------- loss = sum p log p  (= -entropy) --------------------------
__global__ __launch_bounds__(256) void entropy_kernel(
    const float* __restrict__ counts, float* __restrict__ loss_out) {
  __shared__ double sh[256];
  int tid = threadIdx.x;
  double s = 0.0;
  for (int i = tid; i < 1024; i += 256) s += (double)counts[i] + 1e-6;
  sh[tid] = s; __syncthreads();
  for (int off = 128; off > 0; off >>= 1) {
    if (tid < off) sh[tid] += sh[tid + off];
    __syncthreads();
  }
  double S = sh[0];
  __syncthreads();
  double pl = 0.0;
  for (int i = tid; i < 1024; i += 256) {
    double p = ((double)counts[i] + 1e-6) / S;
    pl += p * log(p);
  }
  sh[tid] = pl; __syncthreads();
  for (int off = 128; off > 0; off >>= 1) {
    if (tid < off) sh[tid] += sh[tid + off];
    __syncthreads();
  }
  if (tid == 0) loss_out[0] = (float)sh[0];
}

// ---------------------------------------------------------------------------
extern "C" void kernel_launch(void* const* d_in, const int* in_sizes, int n_in,
                              void* d_out, int out_size, void* d_ws, size_t ws_size,
                              hipStream_t stream) {
  (void)in_sizes; (void)n_in; (void)out_size; (void)ws_size;
  const float* x          = (const float*)d_in[0];
  const float* enc_in_w   = (const float*)d_in[1];
  const float* enc_in_b   = (const float*)d_in[2];
  const float* enc_res_w1 = (const float*)d_in[3];
  const float* enc_res_b1 = (const float*)d_in[4];
  const float* enc_res_w2 = (const float*)d_in[5];
  const float* enc_res_b2 = (const float*)d_in[6];
  const float* enc_down_w = (const float*)d_in[7];
  const float* enc_down_b = (const float*)d_in[8];
  const float* enc_out_w  = (const float*)d_in[9];
  const float* enc_out_b  = (const float*)d_in[10];
  const float* dec_in_w   = (const float*)d_in[11];
  const float* dec_in_b   = (const float*)d_in[12];
  const float* dec_res_w1 = (const float*)d_in[13];
  const float* dec_res_b1 = (const float*)d_in[14];
  const float* dec_res_w2 = (const float*)d_in[15];
  const float* dec_res_b2 = (const float*)d_in[16];
  const float* dec_up_w   = (const float*)d_in[17];
  const float* dec_up_b   = (const float*)d_in[18];
  const float* dec_out_w  = (const float*)d_in[19];
  const float* dec_out_b  = (const float*)d_in[20];
  const float* codebook   = (const float*)d_in[21];
  float* out = (float*)d_out;

  // Workspace: two 128-MiB fp32 buffers.
  const long BIG = 33554432;
  const long S1 = 8388608, S2 = 16777216, S3 = 25165824;
  float* P0 = (float*)d_ws;
  float* P1 = P0 + BIG;
  // Scratch inside d_out (recon overwrites at the very end):
  float2* mr  = (float2*)out;                       // [0, 256) floats
  float* hist = out + 256;                          // [256, 1280)
  unsigned short* WH = (unsigned short*)(out + 2048);   // 147456 bf16 -> [2048, 75776)
  unsigned short* WL = (unsigned short*)(out + 77824);  // [77824, 151552)

  const int W3 = 128 * 128 * 9, W4 = 128 * 128 * 16, BS = 128;

  // conv3x3 MFMA grids: (W/16)*(H/8) px tiles, batch in z
  const dim3 g256(512, 1, 4), g128(128, 1, 4), g64(32, 1, 4);

  // ===================== encoder =====================
  wsplit_kernel<<<576, 256, 0, stream>>>(enc_res_w1, WH, WL);
  conv3x3_mfma_kernel<2><<<g256, 256, 0, stream>>>(
      nullptr, WH, WL, enc_res_b1, P0, 256, 256, nullptr, x, enc_in_w, enc_in_b);
  bn_stats_kernel<<<128, 256, 0, stream>>>(P0, mr, 4, 128, 65536);
  wsplit_kernel<<<576, 256, 0, stream>>>(enc_res_w2, WH, WL);
  conv3x3_mfma_kernel<1><<<g256, 256, 0, stream>>>(
      P0, WH, WL, enc_res_b2, P1, 256, 256, mr, nullptr, nullptr, nullptr);
  bn_stats_kernel<<<128, 256, 0, stream>>>(P1, mr, 4, 128, 65536);
  bn_res_relu_kernel<1><<<dim3(64, 512), 256, 0, stream>>>(
      P1, mr, nullptr, x, enc_in_w, enc_in_b, 16384);
  conv4x4s2_kernel<<<dim3(16, 8, 4), 256, 0, stream>>>(P1, enc_down_w, enc_down_b, P0, 256, 256);

  wsplit_kernel<<<576, 256, 0, stream>>>(enc_res_w1 + W3, WH, WL);
  conv3x3_mfma_kernel<0><<<g128, 256, 0, stream>>>(
      P0, WH, WL, enc_res_b1 + BS, P0 + S1, 128, 128, nullptr, nullptr, nullptr, nullptr);
  bn_stats_kernel<<<128, 256, 0, stream>>>(P0 + S1, mr, 4, 128, 16384);
  wsplit_kernel<<<576, 256, 0, stream>>>(enc_res_w2 + W3, WH, WL);
  conv3x3_mfma_kernel<1><<<g128, 256, 0, stream>>>(
      P0 + S1, WH, WL, enc_res_b2 + BS, P0 + S2, 128, 128, mr, nullptr, nullptr, nullptr);
  bn_stats_kernel<<<128, 256, 0, stream>>>(P0 + S2, mr, 4, 128, 16384);
  bn_res_relu_kernel<0><<<dim3(16, 512), 256, 0, stream>>>(
      P0 + S2, mr, P0, nullptr, nullptr, nullptr, 4096);
  conv4x4s2_kernel<<<dim3(4, 8, 4), 256, 0, stream>>>(
      P0 + S2, enc_down_w + W4, enc_down_b + BS, P0 + S3, 128, 128);

  conv1x1_kernel<0, 16><<<dim3(16, 4), 256, 16 * 128 * 4, stream>>>(
      P0 + S3, enc_out_w, enc_out_b, P1, 4, 128, 64, 4096);

  // ===================== VQ =====================
  zero_kernel<<<4, 256, 0, stream>>>(hist, 1024);
  vq_kernel<<<256, 256, 0, stream>>>(P1, codebook, out + RE_SIZE + 1, hist, 4096);
  entropy_kernel<<<1, 256, 0, stream>>>(hist, out + RE_SIZE);

  // ===================== decoder =====================
  conv1x1_kernel<0, 16><<<dim3(16, 8), 256, 16 * 64 * 4, stream>>>(
      P1, dec_in_w, dec_in_b, P0, 4, 64, 128, 4096);

  wsplit_kernel<<<576, 256, 0, stream>>>(dec_res_w1, WH, WL);
  conv3x3_mfma_kernel<0><<<g64, 256, 0, stream>>>(
      P0, WH, WL, dec_res_b1, P0 + S1, 64, 64, nullptr, nullptr, nullptr, nullptr);
  bn_stats_kernel<<<128, 256, 0, stream>>>(P0 + S1, mr, 4, 128, 4096);
  wsplit_kernel<<<576, 256, 0, stream>>>(dec_res_w2, WH, WL);
  conv3x3_mfma_kernel<1><<<g64, 256, 0, stream>>>(
      P0 + S1, WH, WL, dec_res_b2, P0 + S2, 64, 64, mr, nullptr, nullptr, nullptr);
  bn_stats_kernel<<<128, 256, 0, stream>>>(P0 + S2, mr, 4, 128, 4096);
  bn_res_relu_kernel<0><<<dim3(4, 512), 256, 0, stream>>>(
      P0 + S2, mr, P0, nullptr, nullptr, nullptr, 1024);
  convT4x4_kernel<<<dim3(4, 8, 16), 256, 0, stream>>>(P0 + S2, dec_up_w, dec_up_b, P0 + S3, 64, 64);

  wsplit_kernel<<<576, 256, 0, stream>>>(dec_res_w1 + W3, WH, WL);
  conv3x3_mfma_kernel<0><<<g128, 256, 0, stream>>>(
      P0 + S3, WH, WL, dec_res_b1 + BS, P1, 128, 128, nullptr, nullptr, nullptr, nullptr);
  bn_stats_kernel<<<128, 256, 0, stream>>>(P1, mr, 4, 128, 16384);
  wsplit_kernel<<<576, 256, 0, stream>>>(dec_res_w2 + W3, WH, WL);
  conv3x3_mfma_kernel<1><<<g128, 256, 0, stream>>>(
      P1, WH, WL, dec_res_b2 + BS, P1 + S1, 128, 128, mr, nullptr, nullptr, nullptr);
  bn_stats_kernel<<<128, 256, 0, stream>>>(P1 + S1, mr, 4, 128, 16384);
  bn_res_relu_kernel<0><<<dim3(16, 512), 256, 0, stream>>>(
      P1 + S1, mr, P0 + S3, nullptr, nullptr, nullptr, 4096);
  convT4x4_kernel<<<dim3(16, 8, 16), 256, 0, stream>>>(
      P1 + S1, dec_up_w + W4, dec_up_b + BS, P0, 128, 128);

  conv1x1_kernel<2, 3><<<dim3(256, 1), 256, 3 * 128 * 4, stream>>>(
      P0, dec_out_w, dec_out_b, out, 4, 128, 3, 65536);
}

// Round 8
// 1905.838 us; speedup vs baseline: 6.2356x; 2.8144x over previous
//
#include <hip/hip_runtime.h>
#include <math.h>

// ---------------------------------------------------------------------------
// VQ-VAE forward. R8: precision-tiered split-bf16 MFMA.
//   ENCODER convs (feed z -> idx argmin): 3-way split, 6-term MFMA
//     D = a0b0 + a0b1 + a1b0 + a0b2 + a1b1 + a2b0   (err ~2^-26, fp32-class)
//   DECODER convs (feed recon, loose threshold):    2-way split, 3-term MFMA
// R7 evidence: recon/loss passed, idx failed (950) -> z error ~1.5e-5 from
// 3-term scheme flips near-tie argmins; R6's exact idx was marginal luck.
// Layout/mapping machinery identical to R6/R7 (proven by R6 exactness + R7
// recon pass). Two-stage BN kept.
// ---------------------------------------------------------------------------

#define RE_SIZE 786432

typedef float f32x4 __attribute__((ext_vector_type(4)));
typedef short bf16x8 __attribute__((ext_vector_type(8)));

__device__ __forceinline__ unsigned short f2bf(float f) {
  unsigned u = __float_as_uint(f);
  return (unsigned short)((u + 0x7fffu + ((u >> 16) & 1u)) >> 16);   // RNE
}
__device__ __forceinline__ float bf2f(unsigned short h) {
  return __uint_as_float(((unsigned)h) << 16);
}
__device__ __forceinline__ void split3(float v, unsigned short& a,
                                       unsigned short& b, unsigned short& c) {
  a = f2bf(v); float r = v - bf2f(a);
  b = f2bf(r); r -= bf2f(b);
  c = f2bf(r);
}

// ---------------- conv3x3 weight pre-split (A-frag order, 3 levels) ---------
// [cc4][tap9][mt8][lane64][j8]; co=mt*16+(lane&15); ci=cc*32+(lane>>4)*8+j
__global__ __launch_bounds__(256) void wsplit_kernel(
    const float* __restrict__ w, unsigned short* __restrict__ w0,
    unsigned short* __restrict__ w1, unsigned short* __restrict__ w2) {
  int id = blockIdx.x * 256 + threadIdx.x;        // 576 blocks
  int j = id & 7, lane = (id >> 3) & 63, rest = id >> 9;
  int mt = rest & 7, rest2 = rest >> 3;
  int tap = rest2 % 9, cc = rest2 / 9;
  int co = mt * 16 + (lane & 15);
  int ci = cc * 32 + (lane >> 4) * 8 + j;
  float v = w[((long)co * 128 + ci) * 9 + tap];
  unsigned short a, b, c; split3(v, a, b, c);
  w0[id] = a; w1[id] = b; w2[id] = c;
}

// ---------------- down-conv weight pre-split (3 levels) ---------------------
// [cc8][pair8][mt8][lane64][j8]; tap=pair*2+(q>>1); ci=cc*16+(q&1)*8+j
__global__ __launch_bounds__(256) void wsplit4_kernel(
    const float* __restrict__ w, unsigned short* __restrict__ w0,
    unsigned short* __restrict__ w1, unsigned short* __restrict__ w2) {
  int id = blockIdx.x * 256 + threadIdx.x;        // 1024 blocks
  int j = id & 7, lane = (id >> 3) & 63;
  int mt = (id >> 9) & 7, pair = (id >> 12) & 7, cc = id >> 15;
  int q = lane >> 4;
  int tap = pair * 2 + (q >> 1);
  int ky = tap >> 2, kx = tap & 3;
  int co = mt * 16 + (lane & 15);
  int ci = cc * 16 + (q & 1) * 8 + j;
  float v = w[((long)co * 128 + ci) * 16 + ky * 4 + kx];
  unsigned short a, b, c; split3(v, a, b, c);
  w0[id] = a; w1[id] = b; w2[id] = c;
}

// ---------------- up-conv (convT) weight pre-split (2 levels used) ----------
// [cc4][cls4][j4][mt8][lane64][jj8]; torch w (I,O,4,4).
__global__ __launch_bounds__(256) void wsplitT_kernel(
    const float* __restrict__ w, unsigned short* __restrict__ w0,
    unsigned short* __restrict__ w1) {
  int id = blockIdx.x * 256 + threadIdx.x;        // 1024 blocks
  int jj = id & 7, lane = (id >> 3) & 63;
  int mt = (id >> 9) & 7, j = (id >> 12) & 3, cls = (id >> 14) & 3, cc = id >> 16;
  int py = cls >> 1, px = cls & 1, jy = j >> 1, jx = j & 1;
  int ky = py ? (jy ? 2 : 0) : (jy ? 3 : 1);
  int kx = px ? (jx ? 2 : 0) : (jx ? 3 : 1);
  int co = mt * 16 + (lane & 15);
  int ci = cc * 32 + (lane >> 4) * 8 + jj;
  float v = w[((long)ci * 128 + co) * 16 + ky * 4 + kx];
  unsigned short h = f2bf(v);
  w0[id] = h;
  w1[id] = f2bf(v - bf2f(h));
}

// ---------------- conv 3x3 s1 p1, 128->128, +bias — split-bf16 MFMA ---------
// IMODE: 0 raw; 1 bn+relu fused; 2 enc_in(x) on-the-fly. SPLIT: 2 or 3.
template<int IMODE, int SPLIT>
__global__ __launch_bounds__(256) void conv3x3_mfma_kernel(
    const float* __restrict__ in, const unsigned short* __restrict__ w0s,
    const unsigned short* __restrict__ w1s, const unsigned short* __restrict__ w2s,
    const float* __restrict__ bias, float* __restrict__ out, int H, int W,
    const float2* __restrict__ mr, const float* __restrict__ xin,
    const float* __restrict__ w1, const float* __restrict__ b1) {
  __shared__ __align__(16) unsigned short s_x[SPLIT][5760];  // [cig4][px180][8ci]
  int tid = threadIdx.x, wv = tid >> 6, lane = tid & 63;
  int q = lane >> 4, c15 = lane & 15;
  int tilesX = W >> 4;
  int tx0 = (blockIdx.x % tilesX) << 4;
  int ty0 = (blockIdx.x / tilesX) << 3;
  int n = blockIdx.z;
  long HWl = (long)H * W;
  long ibase = (long)n * 128 * HWl;
  f32x4 acc[2][8];
#pragma unroll
  for (int a = 0; a < 2; ++a)
#pragma unroll
    for (int b = 0; b < 8; ++b) acc[a][b] = (f32x4){0.f, 0.f, 0.f, 0.f};

  for (int cc = 0; cc < 4; ++cc) {
    __syncthreads();
    for (int l = tid; l < 720; l += 256) {
      int cig = l / 180, px = l % 180;
      int y = px / 18, x = px % 18;
      int gy = ty0 + y - 1, gx = tx0 + x - 1;
      float v[8];
      if ((unsigned)gy < (unsigned)H && (unsigned)gx < (unsigned)W) {
        if (IMODE == 2) {
          const float* xp = xin + (long)n * 3 * HWl + (long)gy * W + gx;
          float x0 = xp[0], x1 = xp[HWl], x2 = xp[2 * HWl];
#pragma unroll
          for (int c = 0; c < 8; ++c) {
            int ci = cc * 32 + cig * 8 + c;
            v[c] = fmaf(w1[ci * 3 + 0], x0,
                   fmaf(w1[ci * 3 + 1], x1,
                   fmaf(w1[ci * 3 + 2], x2, b1[ci])));
          }
        } else {
          const float* ip = in + ibase + (long)(cc * 32 + cig * 8) * HWl
                            + (long)gy * W + gx;
#pragma unroll
          for (int c = 0; c < 8; ++c) v[c] = ip[(long)c * HWl];
          if (IMODE == 1) {
#pragma unroll
            for (int c = 0; c < 8; ++c) {
              float2 s = mr[cc * 32 + cig * 8 + c];
              v[c] = fmaxf((v[c] - s.x) * s.y, 0.f);
            }
          }
        }
      } else {
#pragma unroll
        for (int c = 0; c < 8; ++c) v[c] = 0.f;
      }
      bf16x8 sv[SPLIT];
#pragma unroll
      for (int c = 0; c < 8; ++c) {
        unsigned short h0 = f2bf(v[c]); float r = v[c] - bf2f(h0);
        unsigned short h1 = f2bf(r);
        sv[0][c] = (short)h0; sv[1][c] = (short)h1;
        if (SPLIT == 3) { r -= bf2f(h1); sv[2][c] = (short)f2bf(r); }
      }
#pragma unroll
      for (int s = 0; s < SPLIT; ++s) *(bf16x8*)(s_x[s] + l * 8) = sv[s];
    }
    __syncthreads();

    for (int tap = 0; tap < 9; ++tap) {
      int dy = tap / 3, dx = tap % 3;
      long fbase = (long)((cc * 9 + tap) * 8) * 64;
      bf16x8 a0[2], a1[2], a2[2];
#pragma unroll
      for (int m = 0; m < 2; ++m) {
        long fi = fbase + (2 * wv + m) * 64 + lane;
        a0[m] = ((const bf16x8*)w0s)[fi];
        a1[m] = ((const bf16x8*)w1s)[fi];
        if (SPLIT == 3) a2[m] = ((const bf16x8*)w2s)[fi];
      }
      int xoff = (q * 180 + dy * 18 + c15 + dx) * 8;
#pragma unroll
      for (int nn = 0; nn < 8; ++nn) {
        bf16x8 b0 = *(const bf16x8*)(s_x[0] + xoff + nn * 144);
        bf16x8 b1v = *(const bf16x8*)(s_x[1] + xoff + nn * 144);
#pragma unroll
        for (int m = 0; m < 2; ++m) {
          acc[m][nn] = __builtin_amdgcn_mfma_f32_16x16x32_bf16(a0[m], b0, acc[m][nn], 0, 0, 0);
          acc[m][nn] = __builtin_amdgcn_mfma_f32_16x16x32_bf16(a0[m], b1v, acc[m][nn], 0, 0, 0);
          acc[m][nn] = __builtin_amdgcn_mfma_f32_16x16x32_bf16(a1[m], b0, acc[m][nn], 0, 0, 0);
        }
        if (SPLIT == 3) {
          bf16x8 b2 = *(const bf16x8*)(s_x[2] + xoff + nn * 144);
#pragma unroll
          for (int m = 0; m < 2; ++m) {
            acc[m][nn] = __builtin_amdgcn_mfma_f32_16x16x32_bf16(a0[m], b2, acc[m][nn], 0, 0, 0);
            acc[m][nn] = __builtin_amdgcn_mfma_f32_16x16x32_bf16(a1[m], b1v, acc[m][nn], 0, 0, 0);
            acc[m][nn] = __builtin_amdgcn_mfma_f32_16x16x32_bf16(a2[m], b0, acc[m][nn], 0, 0, 0);
          }
        }
      }
    }
  }
#pragma unroll
  for (int mt2 = 0; mt2 < 2; ++mt2) {
    int co0 = (wv * 2 + mt2) * 16 + q * 4;
#pragma unroll
    for (int nn = 0; nn < 8; ++nn) {
      long pxoff = ibase + (long)(ty0 + nn) * W + tx0 + c15;
#pragma unroll
      for (int r = 0; r < 4; ++r)
        out[pxoff + (long)(co0 + r) * HWl] = acc[mt2][nn][r] + bias[co0 + r];
    }
  }
}

// ---------------- conv 4x4 s2 p1, 128->128, +bias +relu — MFMA, 3-split -----
__global__ __launch_bounds__(256) void down_mfma_kernel(
    const float* __restrict__ in, const unsigned short* __restrict__ w0s,
    const unsigned short* __restrict__ w1s, const unsigned short* __restrict__ w2s,
    const float* __restrict__ bias, float* __restrict__ out, int Hin, int Win) {
  __shared__ __align__(16) unsigned short s_x[3][9792];   // [cig2][g4][9*17][8]
  int tid = threadIdx.x, wv = tid >> 6, lane = tid & 63;
  int q = lane >> 4, c15 = lane & 15;
  int Hout = Hin >> 1, Wout = Win >> 1;
  int tilesX = Wout >> 4;
  int tx0 = (blockIdx.x % tilesX) << 4;
  int ty0 = (blockIdx.x / tilesX) << 3;
  int n = blockIdx.z;
  long HWin = (long)Hin * Win, HWout = (long)Hout * Wout;
  long ibase = (long)n * 128 * HWin, obase = (long)n * 128 * HWout;
  f32x4 acc[2][8];
#pragma unroll
  for (int a = 0; a < 2; ++a)
#pragma unroll
    for (int b = 0; b < 8; ++b) acc[a][b] = (f32x4){0.f, 0.f, 0.f, 0.f};

  for (int cc = 0; cc < 8; ++cc) {
    __syncthreads();
    for (int l = tid; l < 1224; l += 256) {
      int cig = l / 612, rem = l % 612;
      int g = rem / 153, p = rem % 153;
      int py = p / 17, px_ = p % 17;
      int gy = g >> 1, gx = g & 1;
      int iy = 2 * (ty0 + py - gy) + gy;
      int ix = 2 * (tx0 + px_ - gx) + gx;
      float v[8];
      if ((unsigned)iy < (unsigned)Hin && (unsigned)ix < (unsigned)Win) {
        const float* ip = in + ibase + (long)(cc * 16 + cig * 8) * HWin
                          + (long)iy * Win + ix;
#pragma unroll
        for (int c = 0; c < 8; ++c) v[c] = ip[(long)c * HWin];
      } else {
#pragma unroll
        for (int c = 0; c < 8; ++c) v[c] = 0.f;
      }
      bf16x8 s0, s1, s2;
#pragma unroll
      for (int c = 0; c < 8; ++c) {
        unsigned short h0, h1, h2; split3(v[c], h0, h1, h2);
        s0[c] = (short)h0; s1[c] = (short)h1; s2[c] = (short)h2;
      }
      *(bf16x8*)(s_x[0] + l * 8) = s0;
      *(bf16x8*)(s_x[1] + l * 8) = s1;
      *(bf16x8*)(s_x[2] + l * 8) = s2;
    }
    __syncthreads();

    for (int pr = 0; pr < 8; ++pr) {
      long fbase = (long)((cc * 8 + pr) * 8) * 64;
      bf16x8 a0[2], a1[2], a2[2];
#pragma unroll
      for (int m = 0; m < 2; ++m) {
        long fi = fbase + (2 * wv + m) * 64 + lane;
        a0[m] = ((const bf16x8*)w0s)[fi];
        a1[m] = ((const bf16x8*)w1s)[fi];
        a2[m] = ((const bf16x8*)w2s)[fi];
      }
      int tap = pr * 2 + (q >> 1);
      int ky = tap >> 2, kx = tap & 3;
      int gy = (ky + 1) & 1, gx = (kx + 1) & 1;
      int dy = (ky == 0) ? -1 : ((ky == 3) ? 1 : 0);
      int dx = (kx == 0) ? -1 : ((kx == 3) ? 1 : 0);
      int g = gy * 2 + gx, cig = q & 1;
      int xoff = ((cig * 4 + g) * 153 + (dy + gy) * 17 + (c15 + dx + gx)) * 8;
#pragma unroll
      for (int nn = 0; nn < 8; ++nn) {
        bf16x8 b0 = *(const bf16x8*)(s_x[0] + xoff + nn * 136);
        bf16x8 b1v = *(const bf16x8*)(s_x[1] + xoff + nn * 136);
        bf16x8 b2 = *(const bf16x8*)(s_x[2] + xoff + nn * 136);
#pragma unroll
        for (int m = 0; m < 2; ++m) {
          acc[m][nn] = __builtin_amdgcn_mfma_f32_16x16x32_bf16(a0[m], b0, acc[m][nn], 0, 0, 0);
          acc[m][nn] = __builtin_amdgcn_mfma_f32_16x16x32_bf16(a0[m], b1v, acc[m][nn], 0, 0, 0);
          acc[m][nn] = __builtin_amdgcn_mfma_f32_16x16x32_bf16(a1[m], b0, acc[m][nn], 0, 0, 0);
          acc[m][nn] = __builtin_amdgcn_mfma_f32_16x16x32_bf16(a0[m], b2, acc[m][nn], 0, 0, 0);
          acc[m][nn] = __builtin_amdgcn_mfma_f32_16x16x32_bf16(a1[m], b1v, acc[m][nn], 0, 0, 0);
          acc[m][nn] = __builtin_amdgcn_mfma_f32_16x16x32_bf16(a2[m], b0, acc[m][nn], 0, 0, 0);
        }
      }
    }
  }
#pragma unroll
  for (int mt2 = 0; mt2 < 2; ++mt2) {
    int co0 = (wv * 2 + mt2) * 16 + q * 4;
#pragma unroll
    for (int nn = 0; nn < 8; ++nn) {
      long pxoff = obase + (long)(ty0 + nn) * Wout + tx0 + c15;
#pragma unroll
      for (int r = 0; r < 4; ++r)
        out[pxoff + (long)(co0 + r) * HWout] =
            fmaxf(acc[mt2][nn][r] + bias[co0 + r], 0.f);
    }
  }
}

// ---------------- ConvTranspose 4x4 s2 p1, +bias +relu — MFMA, 2-split ------
__global__ __launch_bounds__(256) void up_mfma_kernel(
    const float* __restrict__ in, const unsigned short* __restrict__ wh,
    const unsigned short* __restrict__ wl, const float* __restrict__ bias,
    float* __restrict__ out, int Hin, int Win) {
  __shared__ __align__(16) unsigned short s_xh[5760];   // [cig4][10*18][8]
  __shared__ __align__(16) unsigned short s_xl[5760];
  int tid = threadIdx.x, wv = tid >> 6, lane = tid & 63;
  int q = lane >> 4, c15 = lane & 15;
  int cls = blockIdx.z & 3, n = blockIdx.z >> 2;
  int py = cls >> 1, px = cls & 1;
  int Hout = Hin << 1, Wout = Win << 1;
  int tilesX = Win >> 4;
  int x0 = (blockIdx.x % tilesX) << 4;
  int m0 = (blockIdx.x / tilesX) << 3;
  long HWin = (long)Hin * Win, HWout = (long)Hout * Wout;
  long ibase = (long)n * 128 * HWin, obase = (long)n * 128 * HWout;
  f32x4 acc[2][8];
#pragma unroll
  for (int a = 0; a < 2; ++a)
#pragma unroll
    for (int b = 0; b < 8; ++b) acc[a][b] = (f32x4){0.f, 0.f, 0.f, 0.f};

  for (int cc = 0; cc < 4; ++cc) {
    __syncthreads();
    for (int l = tid; l < 720; l += 256) {
      int cig = l / 180, p = l % 180;
      int y = p / 18, x = p % 18;
      int gy = m0 + y - 1, gx = x0 + x - 1;
      float v[8];
      if ((unsigned)gy < (unsigned)Hin && (unsigned)gx < (unsigned)Win) {
        const float* ip = in + ibase + (long)(cc * 32 + cig * 8) * HWin
                          + (long)gy * Win + gx;
#pragma unroll
        for (int c = 0; c < 8; ++c) v[c] = ip[(long)c * HWin];
      } else {
#pragma unroll
        for (int c = 0; c < 8; ++c) v[c] = 0.f;
      }
      bf16x8 hv, lv;
#pragma unroll
      for (int c = 0; c < 8; ++c) {
        unsigned short h = f2bf(v[c]);
        hv[c] = (short)h;
        lv[c] = (short)f2bf(v[c] - bf2f(h));
      }
      *(bf16x8*)(s_xh + l * 8) = hv;
      *(bf16x8*)(s_xl + l * 8) = lv;
    }
    __syncthreads();

#pragma unroll
    for (int j = 0; j < 4; ++j) {
      int jy = j >> 1, jx = j & 1;
      int dy = py ? (jy ? 0 : 1) : (jy ? -1 : 0);
      int dx = px ? (jx ? 0 : 1) : (jx ? -1 : 0);
      long fbase = (long)((((cc * 4 + cls) * 4 + j) * 8)) * 64;
      const bf16x8* aph = (const bf16x8*)wh + fbase;
      const bf16x8* apl = (const bf16x8*)wl + fbase;
      bf16x8 ah0 = aph[(2 * wv) * 64 + lane];
      bf16x8 ah1 = aph[(2 * wv + 1) * 64 + lane];
      bf16x8 al0 = apl[(2 * wv) * 64 + lane];
      bf16x8 al1 = apl[(2 * wv + 1) * 64 + lane];
      int xoff = (q * 180 + (dy + 1) * 18 + (c15 + dx + 1)) * 8;
#pragma unroll
      for (int nn = 0; nn < 8; ++nn) {
        bf16x8 bh = *(const bf16x8*)(s_xh + xoff + nn * 144);
        bf16x8 bl = *(const bf16x8*)(s_xl + xoff + nn * 144);
        acc[0][nn] = __builtin_amdgcn_mfma_f32_16x16x32_bf16(ah0, bh, acc[0][nn], 0, 0, 0);
        acc[0][nn] = __builtin_amdgcn_mfma_f32_16x16x32_bf16(ah0, bl, acc[0][nn], 0, 0, 0);
        acc[0][nn] = __builtin_amdgcn_mfma_f32_16x16x32_bf16(al0, bh, acc[0][nn], 0, 0, 0);
        acc[1][nn] = __builtin_amdgcn_mfma_f32_16x16x32_bf16(ah1, bh, acc[1][nn], 0, 0, 0);
        acc[1][nn] = __builtin_amdgcn_mfma_f32_16x16x32_bf16(ah1, bl, acc[1][nn], 0, 0, 0);
        acc[1][nn] = __builtin_amdgcn_mfma_f32_16x16x32_bf16(al1, bh, acc[1][nn], 0, 0, 0);
      }
    }
  }
#pragma unroll
  for (int mt2 = 0; mt2 < 2; ++mt2) {
    int co0 = (wv * 2 + mt2) * 16 + q * 4;
#pragma unroll
    for (int nn = 0; nn < 8; ++nn) {
      long pxoff = obase + (long)(2 * (m0 + nn) + py) * Wout + 2 * (x0 + c15) + px;
#pragma unroll
      for (int r = 0; r < 4; ++r)
        out[pxoff + (long)(co0 + r) * HWout] =
            fmaxf(acc[mt2][nn][r] + bias[co0 + r], 0.f);
    }
  }
}

// ---------------- conv 1x1 (+bias, ACT: 0=none, 2=sigmoid) ----------------
template<int ACT, int CW>
__global__ __launch_bounds__(256) void conv1x1_kernel(
    const float* __restrict__ in, const float* __restrict__ w,
    const float* __restrict__ bias, float* __restrict__ out,
    int N, int Cin, int Cout, int HW) {
  extern __shared__ float wl[];
  int co0 = blockIdx.y * CW;
  for (int i = threadIdx.x; i < CW * Cin; i += blockDim.x)
    wl[i] = w[(long)co0 * Cin + i];
  __syncthreads();
  int HW4 = HW >> 2;
  long p4 = (long)blockIdx.x * blockDim.x + threadIdx.x;
  if (p4 >= (long)N * HW4) return;
  int n = (int)(p4 / HW4), hw4 = (int)(p4 % HW4);
  const float4* inp = (const float4*)(in + (long)n * Cin * HW) + hw4;
  float4* outp = (float4*)(out + (long)n * Cout * HW) + hw4;
  float4 acc[CW];
#pragma unroll
  for (int j = 0; j < CW; ++j) { float bb = bias[co0 + j]; acc[j] = make_float4(bb, bb, bb, bb); }
  for (int ci = 0; ci < Cin; ++ci) {
    float4 v = inp[(long)ci * HW4];
#pragma unroll
    for (int j = 0; j < CW; ++j) {
      float ww = wl[j * Cin + ci];
      acc[j].x = fmaf(ww, v.x, acc[j].x);
      acc[j].y = fmaf(ww, v.y, acc[j].y);
      acc[j].z = fmaf(ww, v.z, acc[j].z);
      acc[j].w = fmaf(ww, v.w, acc[j].w);
    }
  }
#pragma unroll
  for (int j = 0; j < CW; ++j) {
    float4 v = acc[j];
    if (ACT == 2) {
      v.x = 1.f / (1.f + expf(-v.x));
      v.y = 1.f / (1.f + expf(-v.y));
      v.z = 1.f / (1.f + expf(-v.z));
      v.w = 1.f / (1.f + expf(-v.w));
    }
    outp[(long)(co0 + j) * HW4] = v;
  }
}

// ---------------- BN stats, two-stage ---------------------------------------
__global__ __launch_bounds__(256) void bn_part_kernel(
    const float* __restrict__ x, float2* __restrict__ part, int HW) {
  int c = blockIdx.x, sl = blockIdx.y, tid = threadIdx.x;
  int seg = HW >> 3;
  double s = 0.0, ss = 0.0;
  for (int n = 0; n < 4; ++n) {
    const float4* xp = (const float4*)(x + ((long)(n * 128 + c)) * HW + (long)sl * seg);
    for (int i = tid; i < (seg >> 2); i += 256) {
      float4 v = xp[i];
      s  += (double)v.x + (double)v.y + (double)v.z + (double)v.w;
      ss += (double)v.x * v.x + (double)v.y * v.y + (double)v.z * v.z + (double)v.w * v.w;
    }
  }
  __shared__ double shs[256], shss[256];
  shs[tid] = s; shss[tid] = ss;
  __syncthreads();
  for (int off = 128; off > 0; off >>= 1) {
    if (tid < off) { shs[tid] += shs[tid + off]; shss[tid] += shss[tid + off]; }
    __syncthreads();
  }
  if (tid == 0) part[c * 8 + sl] = make_float2((float)shs[0], (float)shss[0]);
}

__global__ __launch_bounds__(128) void bn_final_kernel(
    const float2* __restrict__ part, float2* __restrict__ mr, float cntf) {
  int c = threadIdx.x;
  if (c < 128) {
    double s = 0.0, ss = 0.0;
#pragma unroll
    for (int i = 0; i < 8; ++i) { float2 p = part[c * 8 + i]; s += p.x; ss += p.y; }
    double cnt = (double)cntf;
    double m = s / cnt;
    double var = ss / cnt - m * m;
    mr[c] = make_float2((float)m, (float)(1.0 / sqrt(var + 1e-5)));
  }
}

// ---------------- in-place: y = relu(bn(y) + residual) ----------------------
template<int RMODE>
__global__ __launch_bounds__(256) void bn_res_relu_kernel(
    float* __restrict__ y, const float2* __restrict__ mr,
    const float* __restrict__ res,
    const float* __restrict__ xin, const float* __restrict__ w1,
    const float* __restrict__ b1, int HW4) {
  int nc = blockIdx.y;
  int c = nc & 127, n = nc >> 7;
  float2 s = mr[c];
  int i = blockIdx.x * blockDim.x + threadIdx.x;
  if (i >= HW4) return;
  long off = (long)nc * HW4 + i;
  float4 v = ((const float4*)y)[off];
  v.x = (v.x - s.x) * s.y; v.y = (v.y - s.x) * s.y;
  v.z = (v.z - s.x) * s.y; v.w = (v.w - s.x) * s.y;
  float4 r4;
  if (RMODE == 0) {
    r4 = ((const float4*)res)[off];
  } else {
    const float4* xp = (const float4*)(xin) + (long)n * 3 * HW4 + i;
    float4 x0 = xp[0], x1 = xp[HW4], x2 = xp[2 * HW4];
    float wa = w1[c * 3 + 0], wb = w1[c * 3 + 1], wc = w1[c * 3 + 2], bb = b1[c];
    r4.x = fmaf(wa, x0.x, fmaf(wb, x1.x, fmaf(wc, x2.x, bb)));
    r4.y = fmaf(wa, x0.y, fmaf(wb, x1.y, fmaf(wc, x2.y, bb)));
    r4.z = fmaf(wa, x0.z, fmaf(wb, x1.z, fmaf(wc, x2.z, bb)));
    r4.w = fmaf(wa, x0.w, fmaf(wb, x1.w, fmaf(wc, x2.w, bb)));
  }
  v.x = fmaxf(v.x + r4.x, 0.f); v.y = fmaxf(v.y + r4.y, 0.f);
  v.z = fmaxf(v.z + r4.z, 0.f); v.w = fmaxf(v.w + r4.w, 0.f);
  ((float4*)y)[off] = v;
}

// ---------------- VQ: argmin_k ||z - e_k||^2, idx + histogram ---------------
__global__ __launch_bounds__(256) void vq_kernel(
    const float* __restrict__ z, const float* __restrict__ cb,
    float* __restrict__ idx_out, float* __restrict__ counts, int HWl) {
  __shared__ float s_z[64][65];
  __shared__ float s_cb[64][64];
  __shared__ float s_bd[4][64];
  __shared__ int   s_bk[4][64];
  int tid = threadIdx.x;
  int r0 = blockIdx.x * 64;
  for (int l = tid; l < 64 * 64; l += 256) {
    int c = l >> 6, rs = l & 63;
    int r = r0 + rs;
    int n = r / HWl, rem = r % HWl;
    s_z[rs][c] = z[((long)(n * 64 + c)) * HWl + rem];
  }
  int row = tid & 63, cg = tid >> 6;
  float best = 3.4e38f; int bestk = 0;
  for (int k0 = 0; k0 < 1024; k0 += 64) {
    __syncthreads();
    for (int l = tid; l < 4096; l += 256)
      s_cb[l >> 6][l & 63] = cb[(long)(k0 + (l >> 6)) * 64 + (l & 63)];
    __syncthreads();
#pragma unroll
    for (int j = 0; j < 16; ++j) {
      int kk = cg * 16 + j;
      const float* zp = s_z[row];
      const float* cp = s_cb[kk];
      float d = 0.f;
#pragma unroll
      for (int c = 0; c < 64; ++c) {
        float t = zp[c] - cp[c];
        d = fmaf(t, t, d);
      }
      int k = k0 + kk;
      if (d < best) { best = d; bestk = k; }
    }
  }
  s_bd[cg][row] = best; s_bk[cg][row] = bestk;
  __syncthreads();
  if (tid < 64) {
    float bd = s_bd[0][tid]; int bk = s_bk[0][tid];
#pragma unroll
    for (int g = 1; g < 4; ++g) {
      float d2 = s_bd[g][tid]; int k2 = s_bk[g][tid];
      if (d2 < bd || (d2 == bd && k2 < bk)) { bd = d2; bk = k2; }
    }
    idx_out[r0 + tid] = (float)bk;
    atomicAdd(&counts[bk], 1.0f);
  }
}

// ---------------- zero small buffer ----------------------------------------
__global__ __launch_bounds__(256) void zero_kernel(float* __restrict__ p, int n) {
  int i = blockIdx.x * 256 + threadIdx.x;
  if (i < n) p[i] = 0.f;
}

// ---------------- loss = sum p log p ----------------------------------------
__global__ __launch_bounds__(256) void entropy_kernel(
    const float* __restrict__ counts, float* __restrict__ loss_out) {
  __shared__ double sh[256];
  int tid = threadIdx.x;
  double s = 0.0;
  for (int i = tid; i < 1024; i += 256) s += (double)counts[i] + 1e-6;
  sh[tid] = s; __syncthreads();
  for (int off = 128; off > 0; off >>= 1) {
    if (tid < off) sh[tid] += sh[tid + off];
    __syncthreads();
  }
  double S = sh[0];
  __syncthreads();
  double pl = 0.0;
  for (int i = tid; i < 1024; i += 256) {
    double p = ((double)counts[i] + 1e-6) / S;
    pl += p * log(p);
  }
  sh[tid] = pl; __syncthreads();
  for (int off = 128; off > 0; off >>= 1) {
    if (tid < off) sh[tid] += sh[tid + off];
    __syncthreads();
  }
  if (tid == 0) loss_out[0] = (float)sh[0];
}

// ---------------------------------------------------------------------------
extern "C" void kernel_launch(void* const* d_in, const int* in_sizes, int n_in,
                              void* d_out, int out_size, void* d_ws, size_t ws_size,
                              hipStream_t stream) {
  (void)in_sizes; (void)n_in; (void)out_size; (void)ws_size;
  const float* x          = (const float*)d_in[0];
  const float* enc_in_w   = (const float*)d_in[1];
  const float* enc_in_b   = (const float*)d_in[2];
  const float* enc_res_w1 = (const float*)d_in[3];
  const float* enc_res_b1 = (const float*)d_in[4];
  const float* enc_res_w2 = (const float*)d_in[5];
  const float* enc_res_b2 = (const float*)d_in[6];
  const float* enc_down_w = (const float*)d_in[7];
  const float* enc_down_b = (const float*)d_in[8];
  const float* enc_out_w  = (const float*)d_in[9];
  const float* enc_out_b  = (const float*)d_in[10];
  const float* dec_in_w   = (const float*)d_in[11];
  const float* dec_in_b   = (const float*)d_in[12];
  const float* dec_res_w1 = (const float*)d_in[13];
  const float* dec_res_b1 = (const float*)d_in[14];
  const float* dec_res_w2 = (const float*)d_in[15];
  const float* dec_res_b2 = (const float*)d_in[16];
  const float* dec_up_w   = (const float*)d_in[17];
  const float* dec_up_b   = (const float*)d_in[18];
  const float* dec_out_w  = (const float*)d_in[19];
  const float* dec_out_b  = (const float*)d_in[20];
  const float* codebook   = (const float*)d_in[21];
  float* out = (float*)d_out;

  const long BIG = 33554432;
  const long S1 = 8388608, S2 = 16777216, S3 = 25165824;
  float* P0 = (float*)d_ws;
  float* P1 = P0 + BIG;
  // d_out scratch (recon overwrites at the very end; idx/loss live past it):
  float2* mr   = (float2*)out;                          // [0,256)
  float* hist  = out + 256;                             // [256,1280)
  float2* part = (float2*)(out + 1280);                 // [1280,3328)
  unsigned short* W0 = (unsigned short*)(out + 4096);   // 262144 shorts each
  unsigned short* W1 = (unsigned short*)(out + 135168);
  unsigned short* W2 = (unsigned short*)(out + 266240);

  const int W3 = 128 * 128 * 9, W4 = 128 * 128 * 16, BS = 128;
  const dim3 g256(512, 1, 4), g128(128, 1, 4), g64(32, 1, 4);

  // ===================== encoder (SPLIT=3, fp32-class) =====================
  wsplit_kernel<<<576, 256, 0, stream>>>(enc_res_w1, W0, W1, W2);
  conv3x3_mfma_kernel<2, 3><<<g256, 256, 0, stream>>>(
      nullptr, W0, W1, W2, enc_res_b1, P0, 256, 256, nullptr, x, enc_in_w, enc_in_b);
  bn_part_kernel<<<dim3(128, 8), 256, 0, stream>>>(P0, part, 65536);
  bn_final_kernel<<<1, 128, 0, stream>>>(part, mr, 262144.f);
  wsplit_kernel<<<576, 256, 0, stream>>>(enc_res_w2, W0, W1, W2);
  conv3x3_mfma_kernel<1, 3><<<g256, 256, 0, stream>>>(
      P0, W0, W1, W2, enc_res_b2, P1, 256, 256, mr, nullptr, nullptr, nullptr);
  bn_part_kernel<<<dim3(128, 8), 256, 0, stream>>>(P1, part, 65536);
  bn_final_kernel<<<1, 128, 0, stream>>>(part, mr, 262144.f);
  bn_res_relu_kernel<1><<<dim3(64, 512), 256, 0, stream>>>(
      P1, mr, nullptr, x, enc_in_w, enc_in_b, 16384);
  wsplit4_kernel<<<1024, 256, 0, stream>>>(enc_down_w, W0, W1, W2);
  down_mfma_kernel<<<g128, 256, 0, stream>>>(P1, W0, W1, W2, enc_down_b, P0, 256, 256);

  wsplit_kernel<<<576, 256, 0, stream>>>(enc_res_w1 + W3, W0, W1, W2);
  conv3x3_mfma_kernel<0, 3><<<g128, 256, 0, stream>>>(
      P0, W0, W1, W2, enc_res_b1 + BS, P0 + S1, 128, 128, nullptr, nullptr, nullptr, nullptr);
  bn_part_kernel<<<dim3(128, 8), 256, 0, stream>>>(P0 + S1, part, 16384);
  bn_final_kernel<<<1, 128, 0, stream>>>(part, mr, 65536.f);
  wsplit_kernel<<<576, 256, 0, stream>>>(enc_res_w2 + W3, W0, W1, W2);
  conv3x3_mfma_kernel<1, 3><<<g128, 256, 0, stream>>>(
      P0 + S1, W0, W1, W2, enc_res_b2 + BS, P0 + S2, 128, 128, mr, nullptr, nullptr, nullptr);
  bn_part_kernel<<<dim3(128, 8), 256, 0, stream>>>(P0 + S2, part, 16384);
  bn_final_kernel<<<1, 128, 0, stream>>>(part, mr, 65536.f);
  bn_res_relu_kernel<0><<<dim3(16, 512), 256, 0, stream>>>(
      P0 + S2, mr, P0, nullptr, nullptr, nullptr, 4096);
  wsplit4_kernel<<<1024, 256, 0, stream>>>(enc_down_w + W4, W0, W1, W2);
  down_mfma_kernel<<<g64, 256, 0, stream>>>(P0 + S2, W0, W1, W2, enc_down_b + BS, P0 + S3, 128, 128);

  conv1x1_kernel<0, 16><<<dim3(16, 4), 256, 16 * 128 * 4, stream>>>(
      P0 + S3, enc_out_w, enc_out_b, P1, 4, 128, 64, 4096);

  // ===================== VQ =====================
  zero_kernel<<<4, 256, 0, stream>>>(hist, 1024);
  vq_kernel<<<256, 256, 0, stream>>>(P1, codebook, out + RE_SIZE + 1, hist, 4096);
  entropy_kernel<<<1, 256, 0, stream>>>(hist, out + RE_SIZE);

  // ===================== decoder (SPLIT=2, fast) =====================
  conv1x1_kernel<0, 16><<<dim3(16, 8), 256, 16 * 64 * 4, stream>>>(
      P1, dec_in_w, dec_in_b, P0, 4, 64, 128, 4096);

  wsplit_kernel<<<576, 256, 0, stream>>>(dec_res_w1, W0, W1, W2);
  conv3x3_mfma_kernel<0, 2><<<g64, 256, 0, stream>>>(
      P0, W0, W1, W2, dec_res_b1, P0 + S1, 64, 64, nullptr, nullptr, nullptr, nullptr);
  bn_part_kernel<<<dim3(128, 8), 256, 0, stream>>>(P0 + S1, part, 4096);
  bn_final_kernel<<<1, 128, 0, stream>>>(part, mr, 16384.f);
  wsplit_kernel<<<576, 256, 0, stream>>>(dec_res_w2, W0, W1, W2);
  conv3x3_mfma_kernel<1, 2><<<g64, 256, 0, stream>>>(
      P0 + S1, W0, W1, W2, dec_res_b2, P0 + S2, 64, 64, mr, nullptr, nullptr, nullptr);
  bn_part_kernel<<<dim3(128, 8), 256, 0, stream>>>(P0 + S2, part, 4096);
  bn_final_kernel<<<1, 128, 0, stream>>>(part, mr, 16384.f);
  bn_res_relu_kernel<0><<<dim3(4, 512), 256, 0, stream>>>(
      P0 + S2, mr, P0, nullptr, nullptr, nullptr, 1024);
  wsplitT_kernel<<<1024, 256, 0, stream>>>(dec_up_w, W0, W1);
  up_mfma_kernel<<<dim3(32, 1, 16), 256, 0, stream>>>(
      P0 + S2, W0, W1, dec_up_b, P0 + S3, 64, 64);

  wsplit_kernel<<<576, 256, 0, stream>>>(dec_res_w1 + W3, W0, W1, W2);
  conv3x3_mfma_kernel<0, 2><<<g128, 256, 0, stream>>>(
      P0 + S3, W0, W1, W2, dec_res_b1 + BS, P1, 128, 128, nullptr, nullptr, nullptr, nullptr);
  bn_part_kernel<<<dim3(128, 8), 256, 0, stream>>>(P1, part, 16384);
  bn_final_kernel<<<1, 128, 0, stream>>>(part, mr, 65536.f);
  wsplit_kernel<<<576, 256, 0, stream>>>(dec_res_w2 + W3, W0, W1, W2);
  conv3x3_mfma_kernel<1, 2><<<g128, 256, 0, stream>>>(
      P1, W0, W1, W2, dec_res_b2 + BS, P1 + S1, 128, 128, mr, nullptr, nullptr, nullptr);
  bn_part_kernel<<<dim3(128, 8), 256, 0, stream>>>(P1 + S1, part, 16384);
  bn_final_kernel<<<1, 128, 0, stream>>>(part, mr, 65536.f);
  bn_res_relu_kernel<0><<<dim3(16, 512), 256, 0, stream>>>(
      P1 + S1, mr, P0 + S3, nullptr, nullptr, nullptr, 4096);
  wsplitT_kernel<<<1024, 256, 0, stream>>>(dec_up_w + W4, W0, W1);
  up_mfma_kernel<<<dim3(128, 1, 16), 256, 0, stream>>>(
      P1 + S1, W0, W1, dec_up_b + BS, P0, 128, 128);

  conv1x1_kernel<2, 3><<<dim3(256, 1), 256, 3 * 128 * 4, stream>>>(
      P0, dec_out_w, dec_out_b, out, 4, 128, 3, 65536);
}

// Round 10
// 1650.839 us; speedup vs baseline: 7.1987x; 1.1545x over previous
//
#include <hip/hip_runtime.h>
#include <math.h>

// ---------------------------------------------------------------------------
// VQ-VAE forward. R10 = R8 (1.906 ms, PASSED) + exactly ONE change:
//   encoder conv1 fused with enc_in (conv36): W_eff[co][tap][4ch] combined in
//   fp64 on device (4th ch = ones -> exact bias-under-padding), K=36 padded
//   to 64, 3-split/6-term MFMA. 12 fp32 accum roundings vs R8's 216 -> better
//   numerics than the path it replaces.
// Everything else is R8 VERBATIM: two-stage BN stats (double), bn_res_relu
// residual passes, R8 down/up MFMA kernels (no buffer aliasing), R8 VQ.
// R9 post-mortem: bundled 4 changes, idx failed, couldn't attribute; also
// found latent up1 read/write overlap (res inside out region) - avoided here
// by reverting to R8's unfused decoder structure.
// ---------------------------------------------------------------------------

#define RE_SIZE 786432

typedef float f32x4 __attribute__((ext_vector_type(4)));
typedef short bf16x8 __attribute__((ext_vector_type(8)));
typedef short bf16x4 __attribute__((ext_vector_type(4)));

__device__ __forceinline__ unsigned short f2bf(float f) {
  unsigned u = __float_as_uint(f);
  return (unsigned short)((u + 0x7fffu + ((u >> 16) & 1u)) >> 16);   // RNE
}
__device__ __forceinline__ float bf2f(unsigned short h) {
  return __uint_as_float(((unsigned)h) << 16);
}
__device__ __forceinline__ void split3(float v, unsigned short& a,
                                       unsigned short& b, unsigned short& c) {
  a = f2bf(v); float r = v - bf2f(a);
  b = f2bf(r); r -= bf2f(b);
  c = f2bf(r);
}

// ---------------- fused enc_in∘conv1 weights, A-frag order, K=64(36) --------
// [kc2][mt8][lane64][j8]; k=kc*32+q*8+j; t=k>>2 (tap), c=k&3 (ch; 3=bias/ones)
__global__ __launch_bounds__(256) void weff_kernel(
    const float* __restrict__ w3, const float* __restrict__ ew,
    const float* __restrict__ eb, unsigned short* __restrict__ f0,
    unsigned short* __restrict__ f1, unsigned short* __restrict__ f2) {
  int id = blockIdx.x * 256 + threadIdx.x;        // 8192
  int j = id & 7, lane = (id >> 3) & 63, mt = (id >> 9) & 7, kc = id >> 12;
  int co = mt * 16 + (lane & 15);
  int q = lane >> 4;
  int k = kc * 32 + q * 8 + j;
  int t = k >> 2, c = k & 3;
  float v = 0.f;
  if (t <= 8) {
    double acc = 0.0;
    for (int ci = 0; ci < 128; ++ci) {
      double wv = (double)w3[((long)co * 128 + ci) * 9 + t];
      double xv = (c < 3) ? (double)ew[ci * 3 + c] : (double)eb[ci];
      acc += wv * xv;
    }
    v = (float)acc;
  }
  unsigned short a, b, cc; split3(v, a, b, cc);
  f0[id] = a; f1[id] = b; f2[id] = cc;
}

// ---------------- encoder conv1: x(+ones) -> 128, K=36, 6-term MFMA ---------
__global__ __launch_bounds__(256) void conv36_mfma_kernel(
    const float* __restrict__ xin, const unsigned short* __restrict__ f0,
    const unsigned short* __restrict__ f1, const unsigned short* __restrict__ f2,
    const float* __restrict__ bias, float* __restrict__ out, int H, int W) {
  __shared__ __align__(16) unsigned short s_x[3][720];   // [y10][x18][ch4]
  int tid = threadIdx.x, wv = tid >> 6, lane = tid & 63;
  int q = lane >> 4, c15 = lane & 15;
  int tilesX = W >> 4;
  int tx0 = (blockIdx.x % tilesX) << 4;
  int ty0 = (blockIdx.x / tilesX) << 3;
  int n = blockIdx.z;
  long HWl = (long)H * W;
  long ibase = (long)n * 128 * HWl;
  long xbase = (long)n * 3 * HWl;
  f32x4 acc[2][8];
#pragma unroll
  for (int a = 0; a < 2; ++a)
#pragma unroll
    for (int b = 0; b < 8; ++b) acc[a][b] = (f32x4){0.f, 0.f, 0.f, 0.f};

  for (int l = tid; l < 180; l += 256) {
    int y = l / 18, x = l % 18;
    int gy = ty0 + y - 1, gx = tx0 + x - 1;
    float v[4] = {0.f, 0.f, 0.f, 0.f};
    if ((unsigned)gy < (unsigned)H && (unsigned)gx < (unsigned)W) {
      const float* xp = xin + xbase + (long)gy * W + gx;
      v[0] = xp[0]; v[1] = xp[HWl]; v[2] = xp[2 * HWl]; v[3] = 1.f;
    }
    bf16x4 s0, s1, s2;
#pragma unroll
    for (int c = 0; c < 4; ++c) {
      unsigned short h0, h1, h2; split3(v[c], h0, h1, h2);
      s0[c] = (short)h0; s1[c] = (short)h1; s2[c] = (short)h2;
    }
    *(bf16x4*)(s_x[0] + l * 4) = s0;
    *(bf16x4*)(s_x[1] + l * 4) = s1;
    *(bf16x4*)(s_x[2] + l * 4) = s2;
  }
  __syncthreads();

#pragma unroll
  for (int kc = 0; kc < 2; ++kc) {
    bf16x8 a0[2], a1[2], a2[2];
#pragma unroll
    for (int m = 0; m < 2; ++m) {
      long fi = (long)(kc * 8 + 2 * wv + m) * 64 + lane;
      a0[m] = ((const bf16x8*)f0)[fi];
      a1[m] = ((const bf16x8*)f1)[fi];
      a2[m] = ((const bf16x8*)f2)[fi];
    }
    int ta = kc * 8 + 2 * q; if (ta > 8) ta = 8;   // clamped taps carry w=0
    int tb = ta + 1;         if (tb > 8) tb = 8;
    int pa_d = (ta / 3) * 18 + ta % 3;
    int pb_d = (tb / 3) * 18 + tb % 3;
#pragma unroll
    for (int nn = 0; nn < 8; ++nn) {
      int pa = (nn * 18 + c15 + pa_d) * 4;
      int pb = (nn * 18 + c15 + pb_d) * 4;
      bf16x8 b0, b1v, b2;
      bf16x4 lo, hi;
      lo = *(const bf16x4*)(s_x[0] + pa); hi = *(const bf16x4*)(s_x[0] + pb);
#pragma unroll
      for (int i = 0; i < 4; ++i) { b0[i] = lo[i]; b0[4 + i] = hi[i]; }
      lo = *(const bf16x4*)(s_x[1] + pa); hi = *(const bf16x4*)(s_x[1] + pb);
#pragma unroll
      for (int i = 0; i < 4; ++i) { b1v[i] = lo[i]; b1v[4 + i] = hi[i]; }
      lo = *(const bf16x4*)(s_x[2] + pa); hi = *(const bf16x4*)(s_x[2] + pb);
#pragma unroll
      for (int i = 0; i < 4; ++i) { b2[i] = lo[i]; b2[4 + i] = hi[i]; }
#pragma unroll
      for (int m = 0; m < 2; ++m) {
        acc[m][nn] = __builtin_amdgcn_mfma_f32_16x16x32_bf16(a0[m], b0, acc[m][nn], 0, 0, 0);
        acc[m][nn] = __builtin_amdgcn_mfma_f32_16x16x32_bf16(a0[m], b1v, acc[m][nn], 0, 0, 0);
        acc[m][nn] = __builtin_amdgcn_mfma_f32_16x16x32_bf16(a1[m], b0, acc[m][nn], 0, 0, 0);
        acc[m][nn] = __builtin_amdgcn_mfma_f32_16x16x32_bf16(a0[m], b2, acc[m][nn], 0, 0, 0);
        acc[m][nn] = __builtin_amdgcn_mfma_f32_16x16x32_bf16(a1[m], b1v, acc[m][nn], 0, 0, 0);
        acc[m][nn] = __builtin_amdgcn_mfma_f32_16x16x32_bf16(a2[m], b0, acc[m][nn], 0, 0, 0);
      }
    }
  }
#pragma unroll
  for (int mt2 = 0; mt2 < 2; ++mt2) {
    int co0 = (wv * 2 + mt2) * 16 + q * 4;
#pragma unroll
    for (int nn = 0; nn < 8; ++nn) {
      long pxoff = ibase + (long)(ty0 + nn) * W + tx0 + c15;
#pragma unroll
      for (int r = 0; r < 4; ++r)
        out[pxoff + (long)(co0 + r) * HWl] = acc[mt2][nn][r] + bias[co0 + r];
    }
  }
}

// ---------------- conv3x3 weight pre-split (A-frag order, 3 levels) ---------
__global__ __launch_bounds__(256) void wsplit_kernel(
    const float* __restrict__ w, unsigned short* __restrict__ w0,
    unsigned short* __restrict__ w1, unsigned short* __restrict__ w2) {
  int id = blockIdx.x * 256 + threadIdx.x;        // 576 blocks
  int j = id & 7, lane = (id >> 3) & 63, rest = id >> 9;
  int mt = rest & 7, rest2 = rest >> 3;
  int tap = rest2 % 9, cc = rest2 / 9;
  int co = mt * 16 + (lane & 15);
  int ci = cc * 32 + (lane >> 4) * 8 + j;
  float v = w[((long)co * 128 + ci) * 9 + tap];
  unsigned short a, b, c; split3(v, a, b, c);
  w0[id] = a; w1[id] = b; w2[id] = c;
}

// ---------------- down-conv weight pre-split (3 levels) ---------------------
__global__ __launch_bounds__(256) void wsplit4_kernel(
    const float* __restrict__ w, unsigned short* __restrict__ w0,
    unsigned short* __restrict__ w1, unsigned short* __restrict__ w2) {
  int id = blockIdx.x * 256 + threadIdx.x;        // 1024 blocks
  int j = id & 7, lane = (id >> 3) & 63;
  int mt = (id >> 9) & 7, pair = (id >> 12) & 7, cc = id >> 15;
  int q = lane >> 4;
  int tap = pair * 2 + (q >> 1);
  int ky = tap >> 2, kx = tap & 3;
  int co = mt * 16 + (lane & 15);
  int ci = cc * 16 + (q & 1) * 8 + j;
  float v = w[((long)co * 128 + ci) * 16 + ky * 4 + kx];
  unsigned short a, b, c; split3(v, a, b, c);
  w0[id] = a; w1[id] = b; w2[id] = c;
}

// ---------------- up-conv (convT) weight pre-split (2 levels) ---------------
__global__ __launch_bounds__(256) void wsplitT_kernel(
    const float* __restrict__ w, unsigned short* __restrict__ w0,
    unsigned short* __restrict__ w1) {
  int id = blockIdx.x * 256 + threadIdx.x;        // 1024 blocks
  int jj = id & 7, lane = (id >> 3) & 63;
  int mt = (id >> 9) & 7, j = (id >> 12) & 3, cls = (id >> 14) & 3, cc = id >> 16;
  int py = cls >> 1, px = cls & 1, jy = j >> 1, jx = j & 1;
  int ky = py ? (jy ? 2 : 0) : (jy ? 3 : 1);
  int kx = px ? (jx ? 2 : 0) : (jx ? 3 : 1);
  int co = mt * 16 + (lane & 15);
  int ci = cc * 32 + (lane >> 4) * 8 + jj;
  float v = w[((long)ci * 128 + co) * 16 + ky * 4 + kx];
  unsigned short h = f2bf(v);
  w0[id] = h;
  w1[id] = f2bf(v - bf2f(h));
}

// ---------------- conv 3x3 s1 p1, 128->128, +bias — split-bf16 MFMA ---------
// IMODE: 0 raw; 1 bn+relu fused; 2 enc_in(x) on-the-fly. SPLIT: 2 or 3.
template<int IMODE, int SPLIT>
__global__ __launch_bounds__(256) void conv3x3_mfma_kernel(
    const float* __restrict__ in, const unsigned short* __restrict__ w0s,
    const unsigned short* __restrict__ w1s, const unsigned short* __restrict__ w2s,
    const float* __restrict__ bias, float* __restrict__ out, int H, int W,
    const float2* __restrict__ mr, const float* __restrict__ xin,
    const float* __restrict__ w1, const float* __restrict__ b1) {
  __shared__ __align__(16) unsigned short s_x[SPLIT][5760];
  int tid = threadIdx.x, wv = tid >> 6, lane = tid & 63;
  int q = lane >> 4, c15 = lane & 15;
  int tilesX = W >> 4;
  int tx0 = (blockIdx.x % tilesX) << 4;
  int ty0 = (blockIdx.x / tilesX) << 3;
  int n = blockIdx.z;
  long HWl = (long)H * W;
  long ibase = (long)n * 128 * HWl;
  f32x4 acc[2][8];
#pragma unroll
  for (int a = 0; a < 2; ++a)
#pragma unroll
    for (int b = 0; b < 8; ++b) acc[a][b] = (f32x4){0.f, 0.f, 0.f, 0.f};

  for (int cc = 0; cc < 4; ++cc) {
    __syncthreads();
    for (int l = tid; l < 720; l += 256) {
      int cig = l / 180, px = l % 180;
      int y = px / 18, x = px % 18;
      int gy = ty0 + y - 1, gx = tx0 + x - 1;
      float v[8];
      if ((unsigned)gy < (unsigned)H && (unsigned)gx < (unsigned)W) {
        if (IMODE == 2) {
          const float* xp = xin + (long)n * 3 * HWl + (long)gy * W + gx;
          float x0 = xp[0], x1 = xp[HWl], x2 = xp[2 * HWl];
#pragma unroll
          for (int c = 0; c < 8; ++c) {
            int ci = cc * 32 + cig * 8 + c;
            v[c] = fmaf(w1[ci * 3 + 0], x0,
                   fmaf(w1[ci * 3 + 1], x1,
                   fmaf(w1[ci * 3 + 2], x2, b1[ci])));
          }
        } else {
          const float* ip = in + ibase + (long)(cc * 32 + cig * 8) * HWl
                            + (long)gy * W + gx;
#pragma unroll
          for (int c = 0; c < 8; ++c) v[c] = ip[(long)c * HWl];
          if (IMODE == 1) {
#pragma unroll
            for (int c = 0; c < 8; ++c) {
              float2 s = mr[cc * 32 + cig * 8 + c];
              v[c] = fmaxf((v[c] - s.x) * s.y, 0.f);
            }
          }
        }
      } else {
#pragma unroll
        for (int c = 0; c < 8; ++c) v[c] = 0.f;
      }
      bf16x8 sv[SPLIT];
#pragma unroll
      for (int c = 0; c < 8; ++c) {
        unsigned short h0 = f2bf(v[c]); float r = v[c] - bf2f(h0);
        unsigned short h1 = f2bf(r);
        sv[0][c] = (short)h0; sv[1][c] = (short)h1;
        if (SPLIT == 3) { r -= bf2f(h1); sv[2][c] = (short)f2bf(r); }
      }
#pragma unroll
      for (int s = 0; s < SPLIT; ++s) *(bf16x8*)(s_x[s] + l * 8) = sv[s];
    }
    __syncthreads();

    for (int tap = 0; tap < 9; ++tap) {
      int dy = tap / 3, dx = tap % 3;
      long fbase = (long)((cc * 9 + tap) * 8) * 64;
      bf16x8 a0[2], a1[2], a2[2];
#pragma unroll
      for (int m = 0; m < 2; ++m) {
        long fi = fbase + (2 * wv + m) * 64 + lane;
        a0[m] = ((const bf16x8*)w0s)[fi];
        a1[m] = ((const bf16x8*)w1s)[fi];
        if (SPLIT == 3) a2[m] = ((const bf16x8*)w2s)[fi];
      }
      int xoff = (q * 180 + dy * 18 + c15 + dx) * 8;
#pragma unroll
      for (int nn = 0; nn < 8; ++nn) {
        bf16x8 b0 = *(const bf16x8*)(s_x[0] + xoff + nn * 144);
        bf16x8 b1v = *(const bf16x8*)(s_x[1] + xoff + nn * 144);
#pragma unroll
        for (int m = 0; m < 2; ++m) {
          acc[m][nn] = __builtin_amdgcn_mfma_f32_16x16x32_bf16(a0[m], b0, acc[m][nn], 0, 0, 0);
          acc[m][nn] = __builtin_amdgcn_mfma_f32_16x16x32_bf16(a0[m], b1v, acc[m][nn], 0, 0, 0);
          acc[m][nn] = __builtin_amdgcn_mfma_f32_16x16x32_bf16(a1[m], b0, acc[m][nn], 0, 0, 0);
        }
        if (SPLIT == 3) {
          bf16x8 b2 = *(const bf16x8*)(s_x[2] + xoff + nn * 144);
#pragma unroll
          for (int m = 0; m < 2; ++m) {
            acc[m][nn] = __builtin_amdgcn_mfma_f32_16x16x32_bf16(a0[m], b2, acc[m][nn], 0, 0, 0);
            acc[m][nn] = __builtin_amdgcn_mfma_f32_16x16x32_bf16(a1[m], b1v, acc[m][nn], 0, 0, 0);
            acc[m][nn] = __builtin_amdgcn_mfma_f32_16x16x32_bf16(a2[m], b0, acc[m][nn], 0, 0, 0);
          }
        }
      }
    }
  }
#pragma unroll
  for (int mt2 = 0; mt2 < 2; ++mt2) {
    int co0 = (wv * 2 + mt2) * 16 + q * 4;
#pragma unroll
    for (int nn = 0; nn < 8; ++nn) {
      long pxoff = ibase + (long)(ty0 + nn) * W + tx0 + c15;
#pragma unroll
      for (int r = 0; r < 4; ++r)
        out[pxoff + (long)(co0 + r) * HWl] = acc[mt2][nn][r] + bias[co0 + r];
    }
  }
}

// ---------------- conv 4x4 s2 p1, 128->128, +bias +relu — MFMA, 3-split -----
__global__ __launch_bounds__(256) void down_mfma_kernel(
    const float* __restrict__ in, const unsigned short* __restrict__ w0s,
    const unsigned short* __restrict__ w1s, const unsigned short* __restrict__ w2s,
    const float* __restrict__ bias, float* __restrict__ out, int Hin, int Win) {
  __shared__ __align__(16) unsigned short s_x[3][9792];   // [cig2][g4][9*17][8]
  int tid = threadIdx.x, wv = tid >> 6, lane = tid & 63;
  int q = lane >> 4, c15 = lane & 15;
  int Hout = Hin >> 1, Wout = Win >> 1;
  int tilesX = Wout >> 4;
  int tx0 = (blockIdx.x % tilesX) << 4;
  int ty0 = (blockIdx.x / tilesX) << 3;
  int n = blockIdx.z;
  long HWin = (long)Hin * Win, HWout = (long)Hout * Wout;
  long ibase = (long)n * 128 * HWin, obase = (long)n * 128 * HWout;
  f32x4 acc[2][8];
#pragma unroll
  for (int a = 0; a < 2; ++a)
#pragma unroll
    for (int b = 0; b < 8; ++b) acc[a][b] = (f32x4){0.f, 0.f, 0.f, 0.f};

  for (int cc = 0; cc < 8; ++cc) {
    __syncthreads();
    for (int l = tid; l < 1224; l += 256) {
      int cig = l / 612, rem = l % 612;
      int g = rem / 153, p = rem % 153;
      int py = p / 17, px_ = p % 17;
      int gy = g >> 1, gx = g & 1;
      int iy = 2 * (ty0 + py - gy) + gy;
      int ix = 2 * (tx0 + px_ - gx) + gx;
      float v[8];
      if ((unsigned)iy < (unsigned)Hin && (unsigned)ix < (unsigned)Win) {
        const float* ip = in + ibase + (long)(cc * 16 + cig * 8) * HWin
                          + (long)iy * Win + ix;
#pragma unroll
        for (int c = 0; c < 8; ++c) v[c] = ip[(long)c * HWin];
      } else {
#pragma unroll
        for (int c = 0; c < 8; ++c) v[c] = 0.f;
      }
      bf16x8 s0, s1, s2;
#pragma unroll
      for (int c = 0; c < 8; ++c) {
        unsigned short h0, h1, h2; split3(v[c], h0, h1, h2);
        s0[c] = (short)h0; s1[c] = (short)h1; s2[c] = (short)h2;
      }
      *(bf16x8*)(s_x[0] + l * 8) = s0;
      *(bf16x8*)(s_x[1] + l * 8) = s1;
      *(bf16x8*)(s_x[2] + l * 8) = s2;
    }
    __syncthreads();

    for (int pr = 0; pr < 8; ++pr) {
      long fbase = (long)((cc * 8 + pr) * 8) * 64;
      bf16x8 a0[2], a1[2], a2[2];
#pragma unroll
      for (int m = 0; m < 2; ++m) {
        long fi = fbase + (2 * wv + m) * 64 + lane;
        a0[m] = ((const bf16x8*)w0s)[fi];
        a1[m] = ((const bf16x8*)w1s)[fi];
        a2[m] = ((const bf16x8*)w2s)[fi];
      }
      int tap = pr * 2 + (q >> 1);
      int ky = tap >> 2, kx = tap & 3;
      int gy = (ky + 1) & 1, gx = (kx + 1) & 1;
      int dy = (ky == 0) ? -1 : ((ky == 3) ? 1 : 0);
      int dx = (kx == 0) ? -1 : ((kx == 3) ? 1 : 0);
      int g = gy * 2 + gx, cig = q & 1;
      int xoff = ((cig * 4 + g) * 153 + (dy + gy) * 17 + (c15 + dx + gx)) * 8;
#pragma unroll
      for (int nn = 0; nn < 8; ++nn) {
        bf16x8 b0 = *(const bf16x8*)(s_x[0] + xoff + nn * 136);
        bf16x8 b1v = *(const bf16x8*)(s_x[1] + xoff + nn * 136);
        bf16x8 b2 = *(const bf16x8*)(s_x[2] + xoff + nn * 136);
#pragma unroll
        for (int m = 0; m < 2; ++m) {
          acc[m][nn] = __builtin_amdgcn_mfma_f32_16x16x32_bf16(a0[m], b0, acc[m][nn], 0, 0, 0);
          acc[m][nn] = __builtin_amdgcn_mfma_f32_16x16x32_bf16(a0[m], b1v, acc[m][nn], 0, 0, 0);
          acc[m][nn] = __builtin_amdgcn_mfma_f32_16x16x32_bf16(a1[m], b0, acc[m][nn], 0, 0, 0);
          acc[m][nn] = __builtin_amdgcn_mfma_f32_16x16x32_bf16(a0[m], b2, acc[m][nn], 0, 0, 0);
          acc[m][nn] = __builtin_amdgcn_mfma_f32_16x16x32_bf16(a1[m], b1v, acc[m][nn], 0, 0, 0);
          acc[m][nn] = __builtin_amdgcn_mfma_f32_16x16x32_bf16(a2[m], b0, acc[m][nn], 0, 0, 0);
        }
      }
    }
  }
#pragma unroll
  for (int mt2 = 0; mt2 < 2; ++mt2) {
    int co0 = (wv * 2 + mt2) * 16 + q * 4;
#pragma unroll
    for (int nn = 0; nn < 8; ++nn) {
      long pxoff = obase + (long)(ty0 + nn) * Wout + tx0 + c15;
#pragma unroll
      for (int r = 0; r < 4; ++r)
        out[pxoff + (long)(co0 + r) * HWout] =
            fmaxf(acc[mt2][nn][r] + bias[co0 + r], 0.f);
    }
  }
}

// ---------------- ConvTranspose 4x4 s2 p1, +bias +relu — MFMA, 2-split ------
__global__ __launch_bounds__(256) void up_mfma_kernel(
    const float* __restrict__ in, const unsigned short* __restrict__ wh,
    const unsigned short* __restrict__ wl, const float* __restrict__ bias,
    float* __restrict__ out, int Hin, int Win) {
  __shared__ __align__(16) unsigned short s_xh[5760];   // [cig4][10*18][8]
  __shared__ __align__(16) unsigned short s_xl[5760];
  int tid = threadIdx.x, wv = tid >> 6, lane = tid & 63;
  int q = lane >> 4, c15 = lane & 15;
  int cls = blockIdx.z & 3, n = blockIdx.z >> 2;
  int py = cls >> 1, px = cls & 1;
  int Hout = Hin << 1, Wout = Win << 1;
  int tilesX = Win >> 4;
  int x0 = (blockIdx.x % tilesX) << 4;
  int m0 = (blockIdx.x / tilesX) << 3;
  long HWin = (long)Hin * Win, HWout = (long)Hout * Wout;
  long ibase = (long)n * 128 * HWin, obase = (long)n * 128 * HWout;
  f32x4 acc[2][8];
#pragma unroll
  for (int a = 0; a < 2; ++a)
#pragma unroll
    for (int b = 0; b < 8; ++b) acc[a][b] = (f32x4){0.f, 0.f, 0.f, 0.f};

  for (int cc = 0; cc < 4; ++cc) {
    __syncthreads();
    for (int l = tid; l < 720; l += 256) {
      int cig = l / 180, p = l % 180;
      int y = p / 18, x = p % 18;
      int gy = m0 + y - 1, gx = x0 + x - 1;
      float v[8];
      if ((unsigned)gy < (unsigned)Hin && (unsigned)gx < (unsigned)Win) {
        const float* ip = in + ibase + (long)(cc * 32 + cig * 8) * HWin
                          + (long)gy * Win + gx;
#pragma unroll
        for (int c = 0; c < 8; ++c) v[c] = ip[(long)c * HWin];
      } else {
#pragma unroll
        for (int c = 0; c < 8; ++c) v[c] = 0.f;
      }
      bf16x8 hv, lv;
#pragma unroll
      for (int c = 0; c < 8; ++c) {
        unsigned short h = f2bf(v[c]);
        hv[c] = (short)h;
        lv[c] = (short)f2bf(v[c] - bf2f(h));
      }
      *(bf16x8*)(s_xh + l * 8) = hv;
      *(bf16x8*)(s_xl + l * 8) = lv;
    }
    __syncthreads();

#pragma unroll
    for (int j = 0; j < 4; ++j) {
      int jy = j >> 1, jx = j & 1;
      int dy = py ? (jy ? 0 : 1) : (jy ? -1 : 0);
      int dx = px ? (jx ? 0 : 1) : (jx ? -1 : 0);
      long fbase = (long)((((cc * 4 + cls) * 4 + j) * 8)) * 64;
      const bf16x8* aph = (const bf16x8*)wh + fbase;
      const bf16x8* apl = (const bf16x8*)wl + fbase;
      bf16x8 ah0 = aph[(2 * wv) * 64 + lane];
      bf16x8 ah1 = aph[(2 * wv + 1) * 64 + lane];
      bf16x8 al0 = apl[(2 * wv) * 64 + lane];
      bf16x8 al1 = apl[(2 * wv + 1) * 64 + lane];
      int xoff = (q * 180 + (dy + 1) * 18 + (c15 + dx + 1)) * 8;
#pragma unroll
      for (int nn = 0; nn < 8; ++nn) {
        bf16x8 bh = *(const bf16x8*)(s_xh + xoff + nn * 144);
        bf16x8 bl = *(const bf16x8*)(s_xl + xoff + nn * 144);
        acc[0][nn] = __builtin_amdgcn_mfma_f32_16x16x32_bf16(ah0, bh, acc[0][nn], 0, 0, 0);
        acc[0][nn] = __builtin_amdgcn_mfma_f32_16x16x32_bf16(ah0, bl, acc[0][nn], 0, 0, 0);
        acc[0][nn] = __builtin_amdgcn_mfma_f32_16x16x32_bf16(al0, bh, acc[0][nn], 0, 0, 0);
        acc[1][nn] = __builtin_amdgcn_mfma_f32_16x16x32_bf16(ah1, bh, acc[1][nn], 0, 0, 0);
        acc[1][nn] = __builtin_amdgcn_mfma_f32_16x16x32_bf16(ah1, bl, acc[1][nn], 0, 0, 0);
        acc[1][nn] = __builtin_amdgcn_mfma_f32_16x16x32_bf16(al1, bh, acc[1][nn], 0, 0, 0);
      }
    }
  }
#pragma unroll
  for (int mt2 = 0; mt2 < 2; ++mt2) {
    int co0 = (wv * 2 + mt2) * 16 + q * 4;
#pragma unroll
    for (int nn = 0; nn < 8; ++nn) {
      long pxoff = obase + (long)(2 * (m0 + nn) + py) * Wout + 2 * (x0 + c15) + px;
#pragma unroll
      for (int r = 0; r < 4; ++r)
        out[pxoff + (long)(co0 + r) * HWout] =
            fmaxf(acc[mt2][nn][r] + bias[co0 + r], 0.f);
    }
  }
}

// ---------------- conv 1x1 (+bias, ACT: 0=none, 2=sigmoid) ----------------
template<int ACT, int CW>
__global__ __launch_bounds__(256) void conv1x1_kernel(
    const float* __restrict__ in, const float* __restrict__ w,
    const float* __restrict__ bias, float* __restrict__ out,
    int N, int Cin, int Cout, int HW) {
  extern __shared__ float wl[];
  int co0 = blockIdx.y * CW;
  for (int i = threadIdx.x; i < CW * Cin; i += blockDim.x)
    wl[i] = w[(long)co0 * Cin + i];
  __syncthreads();
  int HW4 = HW >> 2;
  long p4 = (long)blockIdx.x * blockDim.x + threadIdx.x;
  if (p4 >= (long)N * HW4) return;
  int n = (int)(p4 / HW4), hw4 = (int)(p4 % HW4);
  const float4* inp = (const float4*)(in + (long)n * Cin * HW) + hw4;
  float4* outp = (float4*)(out + (long)n * Cout * HW) + hw4;
  float4 acc[CW];
#pragma unroll
  for (int j = 0; j < CW; ++j) { float bb = bias[co0 + j]; acc[j] = make_float4(bb, bb, bb, bb); }
  for (int ci = 0; ci < Cin; ++ci) {
    float4 v = inp[(long)ci * HW4];
#pragma unroll
    for (int j = 0; j < CW; ++j) {
      float ww = wl[j * Cin + ci];
      acc[j].x = fmaf(ww, v.x, acc[j].x);
      acc[j].y = fmaf(ww, v.y, acc[j].y);
      acc[j].z = fmaf(ww, v.z, acc[j].z);
      acc[j].w = fmaf(ww, v.w, acc[j].w);
    }
  }
#pragma unroll
  for (int j = 0; j < CW; ++j) {
    float4 v = acc[j];
    if (ACT == 2) {
      v.x = 1.f / (1.f + expf(-v.x));
      v.y = 1.f / (1.f + expf(-v.y));
      v.z = 1.f / (1.f + expf(-v.z));
      v.w = 1.f / (1.f + expf(-v.w));
    }
    outp[(long)(co0 + j) * HW4] = v;
  }
}

// ---------------- BN stats, two-stage ---------------------------------------
__global__ __launch_bounds__(256) void bn_part_kernel(
    const float* __restrict__ x, float2* __restrict__ part, int HW) {
  int c = blockIdx.x, sl = blockIdx.y, tid = threadIdx.x;
  int seg = HW >> 3;
  double s = 0.0, ss = 0.0;
  for (int n = 0; n < 4; ++n) {
    const float4* xp = (const float4*)(x + ((long)(n * 128 + c)) * HW + (long)sl * seg);
    for (int i = tid; i < (seg >> 2); i += 256) {
      float4 v = xp[i];
      s  += (double)v.x + (double)v.y + (double)v.z + (double)v.w;
      ss += (double)v.x * v.x + (double)v.y * v.y + (double)v.z * v.z + (double)v.w * v.w;
    }
  }
  __shared__ double shs[256], shss[256];
  shs[tid] = s; shss[tid] = ss;
  __syncthreads();
  for (int off = 128; off > 0; off >>= 1) {
    if (tid < off) { shs[tid] += shs[tid + off]; shss[tid] += shss[tid + off]; }
    __syncthreads();
  }
  if (tid == 0) part[c * 8 + sl] = make_float2((float)shs[0], (float)shss[0]);
}

__global__ __launch_bounds__(128) void bn_final_kernel(
    const float2* __restrict__ part, float2* __restrict__ mr, float cntf) {
  int c = threadIdx.x;
  if (c < 128) {
    double s = 0.0, ss = 0.0;
#pragma unroll
    for (int i = 0; i < 8; ++i) { float2 p = part[c * 8 + i]; s += p.x; ss += p.y; }
    double cnt = (double)cntf;
    double m = s / cnt;
    double var = ss / cnt - m * m;
    mr[c] = make_float2((float)m, (float)(1.0 / sqrt(var + 1e-5)));
  }
}

// ---------------- in-place: y = relu(bn(y) + residual) ----------------------
template<int RMODE>
__global__ __launch_bounds__(256) void bn_res_relu_kernel(
    float* __restrict__ y, const float2* __restrict__ mr,
    const float* __restrict__ res,
    const float* __restrict__ xin, const float* __restrict__ w1,
    const float* __restrict__ b1, int HW4) {
  int nc = blockIdx.y;
  int c = nc & 127, n = nc >> 7;
  float2 s = mr[c];
  int i = blockIdx.x * blockDim.x + threadIdx.x;
  if (i >= HW4) return;
  long off = (long)nc * HW4 + i;
  float4 v = ((const float4*)y)[off];
  v.x = (v.x - s.x) * s.y; v.y = (v.y - s.x) * s.y;
  v.z = (v.z - s.x) * s.y; v.w = (v.w - s.x) * s.y;
  float4 r4;
  if (RMODE == 0) {
    r4 = ((const float4*)res)[off];
  } else {
    const float4* xp = (const float4*)(xin) + (long)n * 3 * HW4 + i;
    float4 x0 = xp[0], x1 = xp[HW4], x2 = xp[2 * HW4];
    float wa = w1[c * 3 + 0], wb = w1[c * 3 + 1], wc = w1[c * 3 + 2], bb = b1[c];
    r4.x = fmaf(wa, x0.x, fmaf(wb, x1.x, fmaf(wc, x2.x, bb)));
    r4.y = fmaf(wa, x0.y, fmaf(wb, x1.y, fmaf(wc, x2.y, bb)));
    r4.z = fmaf(wa, x0.z, fmaf(wb, x1.z, fmaf(wc, x2.z, bb)));
    r4.w = fmaf(wa, x0.w, fmaf(wb, x1.w, fmaf(wc, x2.w, bb)));
  }
  v.x = fmaxf(v.x + r4.x, 0.f); v.y = fmaxf(v.y + r4.y, 0.f);
  v.z = fmaxf(v.z + r4.z, 0.f); v.w = fmaxf(v.w + r4.w, 0.f);
  ((float4*)y)[off] = v;
}

// ---------------- VQ: argmin_k ||z - e_k||^2, idx + histogram ---------------
__global__ __launch_bounds__(256) void vq_kernel(
    const float* __restrict__ z, const float* __restrict__ cb,
    float* __restrict__ idx_out, float* __restrict__ counts, int HWl) {
  __shared__ float s_z[64][65];
  __shared__ float s_cb[64][64];
  __shared__ float s_bd[4][64];
  __shared__ int   s_bk[4][64];
  int tid = threadIdx.x;
  int r0 = blockIdx.x * 64;
  for (int l = tid; l < 64 * 64; l += 256) {
    int c = l >> 6, rs = l & 63;
    int r = r0 + rs;
    int n = r / HWl, rem = r % HWl;
    s_z[rs][c] = z[((long)(n * 64 + c)) * HWl + rem];
  }
  int row = tid & 63, cg = tid >> 6;
  float best = 3.4e38f; int bestk = 0;
  for (int k0 = 0; k0 < 1024; k0 += 64) {
    __syncthreads();
    for (int l = tid; l < 4096; l += 256)
      s_cb[l >> 6][l & 63] = cb[(long)(k0 + (l >> 6)) * 64 + (l & 63)];
    __syncthreads();
#pragma unroll
    for (int j = 0; j < 16; ++j) {
      int kk = cg * 16 + j;
      const float* zp = s_z[row];
      const float* cp = s_cb[kk];
      float d = 0.f;
#pragma unroll
      for (int c = 0; c < 64; ++c) {
        float t = zp[c] - cp[c];
        d = fmaf(t, t, d);
      }
      int k = k0 + kk;
      if (d < best) { best = d; bestk = k; }
    }
  }
  s_bd[cg][row] = best; s_bk[cg][row] = bestk;
  __syncthreads();
  if (tid < 64) {
    float bd = s_bd[0][tid]; int bk = s_bk[0][tid];
#pragma unroll
    for (int g = 1; g < 4; ++g) {
      float d2 = s_bd[g][tid]; int k2 = s_bk[g][tid];
      if (d2 < bd || (d2 == bd && k2 < bk)) { bd = d2; bk = k2; }
    }
    idx_out[r0 + tid] = (float)bk;
    atomicAdd(&counts[bk], 1.0f);
  }
}

// ---------------- zero small buffer ----------------------------------------
__global__ __launch_bounds__(256) void zero_kernel(float* __restrict__ p, int n) {
  int i = blockIdx.x * 256 + threadIdx.x;
  if (i < n) p[i] = 0.f;
}

// ---------------- loss = sum p log p ----------------------------------------
__global__ __launch_bounds__(256) void entropy_kernel(
    const float* __restrict__ counts, float* __restrict__ loss_out) {
  __shared__ double sh[256];
  int tid = threadIdx.x;
  double s = 0.0;
  for (int i = tid; i < 1024; i += 256) s += (double)counts[i] + 1e-6;
  sh[tid] = s; __syncthreads();
  for (int off = 128; off > 0; off >>= 1) {
    if (tid < off) sh[tid] += sh[tid + off];
    __syncthreads();
  }
  double S = sh[0];
  __syncthreads();
  double pl = 0.0;
  for (int i = tid; i < 1024; i += 256) {
    double p = ((double)counts[i] + 1e-6) / S;
    pl += p * log(p);
  }
  sh[tid] = pl; __syncthreads();
  for (int off = 128; off > 0; off >>= 1) {
    if (tid < off) sh[tid] += sh[tid + off];
    __syncthreads();
  }
  if (tid == 0) loss_out[0] = (float)sh[0];
}

// ---------------------------------------------------------------------------
extern "C" void kernel_launch(void* const* d_in, const int* in_sizes, int n_in,
                              void* d_out, int out_size, void* d_ws, size_t ws_size,
                              hipStream_t stream) {
  (void)in_sizes; (void)n_in; (void)out_size; (void)ws_size;
  const float* x          = (const float*)d_in[0];
  const float* enc_in_w   = (const float*)d_in[1];
  const float* enc_in_b   = (const float*)d_in[2];
  const float* enc_res_w1 = (const float*)d_in[3];
  const float* enc_res_b1 = (const float*)d_in[4];
  const float* enc_res_w2 = (const float*)d_in[5];
  const float* enc_res_b2 = (const float*)d_in[6];
  const float* enc_down_w = (const float*)d_in[7];
  const float* enc_down_b = (const float*)d_in[8];
  const float* enc_out_w  = (const float*)d_in[9];
  const float* enc_out_b  = (const float*)d_in[10];
  const float* dec_in_w   = (const float*)d_in[11];
  const float* dec_in_b   = (const float*)d_in[12];
  const float* dec_res_w1 = (const float*)d_in[13];
  const float* dec_res_b1 = (const float*)d_in[14];
  const float* dec_res_w2 = (const float*)d_in[15];
  const float* dec_res_b2 = (const float*)d_in[16];
  const float* dec_up_w   = (const float*)d_in[17];
  const float* dec_up_b   = (const float*)d_in[18];
  const float* dec_out_w  = (const float*)d_in[19];
  const float* dec_out_b  = (const float*)d_in[20];
  const float* codebook   = (const float*)d_in[21];
  float* out = (float*)d_out;

  const long BIG = 33554432;
  const long S1 = 8388608, S2 = 16777216, S3 = 25165824;
  float* P0 = (float*)d_ws;
  float* P1 = P0 + BIG;
  // d_out scratch (all < RE_SIZE; recon overwrites at the very end):
  float2* mr   = (float2*)out;                          // [0,256)
  float* hist  = out + 256;                             // [256,1280)
  float2* part = (float2*)(out + 1280);                 // [1280,3328)
  unsigned short* W0 = (unsigned short*)(out + 4096);   // 262144 shorts each
  unsigned short* W1 = (unsigned short*)(out + 135168);
  unsigned short* W2 = (unsigned short*)(out + 266240);
  unsigned short* F0 = (unsigned short*)(out + 401408); // weff frags 3x8192 sh
  unsigned short* F1 = F0 + 8192;
  unsigned short* F2 = F1 + 8192;

  const int W3 = 128 * 128 * 9, W4 = 128 * 128 * 16, BS = 128;
  const dim3 g256(512, 1, 4), g128(128, 1, 4), g64(32, 1, 4);

  // ===================== encoder (SPLIT=3, fp32-class) =====================
  weff_kernel<<<32, 256, 0, stream>>>(enc_res_w1, enc_in_w, enc_in_b, F0, F1, F2);
  conv36_mfma_kernel<<<g256, 256, 0, stream>>>(
      x, F0, F1, F2, enc_res_b1, P0, 256, 256);
  bn_part_kernel<<<dim3(128, 8), 256, 0, stream>>>(P0, part, 65536);
  bn_final_kernel<<<1, 128, 0, stream>>>(part, mr, 262144.f);
  wsplit_kernel<<<576, 256, 0, stream>>>(enc_res_w2, W0, W1, W2);
  conv3x3_mfma_kernel<1, 3><<<g256, 256, 0, stream>>>(
      P0, W0, W1, W2, enc_res_b2, P1, 256, 256, mr, nullptr, nullptr, nullptr);
  bn_part_kernel<<<dim3(128, 8), 256, 0, stream>>>(P1, part, 65536);
  bn_final_kernel<<<1, 128, 0, stream>>>(part, mr, 262144.f);
  bn_res_relu_kernel<1><<<dim3(64, 512), 256, 0, stream>>>(
      P1, mr, nullptr, x, enc_in_w, enc_in_b, 16384);
  wsplit4_kernel<<<1024, 256, 0, stream>>>(enc_down_w, W0, W1, W2);
  down_mfma_kernel<<<g128, 256, 0, stream>>>(P1, W0, W1, W2, enc_down_b, P0, 256, 256);

  wsplit_kernel<<<576, 256, 0, stream>>>(enc_res_w1 + W3, W0, W1, W2);
  conv3x3_mfma_kernel<0, 3><<<g128, 256, 0, stream>>>(
      P0, W0, W1, W2, enc_res_b1 + BS, P0 + S1, 128, 128, nullptr, nullptr, nullptr, nullptr);
  bn_part_kernel<<<dim3(128, 8), 256, 0, stream>>>(P0 + S1, part, 16384);
  bn_final_kernel<<<1, 128, 0, stream>>>(part, mr, 65536.f);
  wsplit_kernel<<<576, 256, 0, stream>>>(enc_res_w2 + W3, W0, W1, W2);
  conv3x3_mfma_kernel<1, 3><<<g128, 256, 0, stream>>>(
      P0 + S1, W0, W1, W2, enc_res_b2 + BS, P0 + S2, 128, 128, mr, nullptr, nullptr, nullptr);
  bn_part_kernel<<<dim3(128, 8), 256, 0, stream>>>(P0 + S2, part, 16384);
  bn_final_kernel<<<1, 128, 0, stream>>>(part, mr, 65536.f);
  bn_res_relu_kernel<0><<<dim3(16, 512), 256, 0, stream>>>(
      P0 + S2, mr, P0, nullptr, nullptr, nullptr, 4096);
  wsplit4_kernel<<<1024, 256, 0, stream>>>(enc_down_w + W4, W0, W1, W2);
  down_mfma_kernel<<<g64, 256, 0, stream>>>(P0 + S2, W0, W1, W2, enc_down_b + BS, P0 + S3, 128, 128);

  conv1x1_kernel<0, 16><<<dim3(16, 4), 256, 16 * 128 * 4, stream>>>(
      P0 + S3, enc_out_w, enc_out_b, P1, 4, 128, 64, 4096);

  // ===================== VQ =====================
  zero_kernel<<<4, 256, 0, stream>>>(hist, 1024);
  vq_kernel<<<256, 256, 0, stream>>>(P1, codebook, out + RE_SIZE + 1, hist, 4096);
  entropy_kernel<<<1, 256, 0, stream>>>(hist, out + RE_SIZE);

  // ===================== decoder (SPLIT=2) =====================
  conv1x1_kernel<0, 16><<<dim3(16, 8), 256, 16 * 64 * 4, stream>>>(
      P1, dec_in_w, dec_in_b, P0, 4, 64, 128, 4096);

  wsplit_kernel<<<576, 256, 0, stream>>>(dec_res_w1, W0, W1, W2);
  conv3x3_mfma_kernel<0, 2><<<g64, 256, 0, stream>>>(
      P0, W0, W1, W2, dec_res_b1, P0 + S1, 64, 64, nullptr, nullptr, nullptr, nullptr);
  bn_part_kernel<<<dim3(128, 8), 256, 0, stream>>>(P0 + S1, part, 4096);
  bn_final_kernel<<<1, 128, 0, stream>>>(part, mr, 16384.f);
  wsplit_kernel<<<576, 256, 0, stream>>>(dec_res_w2, W0, W1, W2);
  conv3x3_mfma_kernel<1, 2><<<g64, 256, 0, stream>>>(
      P0 + S1, W0, W1, W2, dec_res_b2, P0 + S2, 64, 64, mr, nullptr, nullptr, nullptr);
  bn_part_kernel<<<dim3(128, 8), 256, 0, stream>>>(P0 + S2, part, 4096);
  bn_final_kernel<<<1, 128, 0, stream>>>(part, mr, 16384.f);
  bn_res_relu_kernel<0><<<dim3(4, 512), 256, 0, stream>>>(
      P0 + S2, mr, P0, nullptr, nullptr, nullptr, 1024);
  wsplitT_kernel<<<1024, 256, 0, stream>>>(dec_up_w, W0, W1);
  up_mfma_kernel<<<dim3(32, 1, 16), 256, 0, stream>>>(
      P0 + S2, W0, W1, dec_up_b, P0 + S3, 64, 64);

  wsplit_kernel<<<576, 256, 0, stream>>>(dec_res_w1 + W3, W0, W1, W2);
  conv3x3_mfma_kernel<0, 2><<<g128, 256, 0, stream>>>(
      P0 + S3, W0, W1, W2, dec_res_b1 + BS, P1, 128, 128, nullptr, nullptr, nullptr, nullptr);
  bn_part_kernel<<<dim3(128, 8), 256, 0, stream>>>(P1, part, 16384);
  bn_final_kernel<<<1, 128, 0, stream>>>(part, mr, 65536.f);
  wsplit_kernel<<<576, 256, 0, stream>>>(dec_res_w2 + W3, W0, W1, W2);
  conv3x3_mfma_kernel<1, 2><<<g128, 256, 0, stream>>>(
      P1, W0, W1, W2, dec_res_b2 + BS, P1 + S1, 128, 128, mr, nullptr, nullptr, nullptr);
  bn_part_kernel<<<dim3(128, 8), 256, 0, stream>>>(P1 + S1, part, 16384);
  bn_final_kernel<<<1, 128, 0, stream>>>(part, mr, 65536.f);
  bn_res_relu_kernel<0><<<dim3(16, 512), 256, 0, stream>>>(
      P1 + S1, mr, P0 + S3, nullptr, nullptr, nullptr, 4096);
  wsplitT_kernel<<<1024, 256, 0, stream>>>(dec_up_w + W4, W0, W1);
  up_mfma_kernel<<<dim3(128, 1, 16), 256, 0, stream>>>(
      P1 + S1, W0, W1, dec_up_b + BS, P0, 128, 128);

  conv1x1_kernel<2, 3><<<dim3(256, 1), 256, 3 * 128 * 4, stream>>>(
      P0, dec_out_w, dec_out_b, out, 4, 128, 3, 65536);
}